// Round 11
// baseline (962.609 us; speedup 1.0000x reference)
//
#include <hip/hip_runtime.h>
#include <hip/hip_fp16.h>

#define WPB 8     // waves per sage block (512 threads)
#define PADK 136  // f16 elems per LDS row: 128 + 8 pad (16B-aligned rows)
#define BSH 8     // bucket shift: 256 nodes per bucket
#define BNODES 256
#define SC_BLOCKS 256

typedef _Float16 half8 __attribute__((ext_vector_type(8)));
typedef float floatx4 __attribute__((ext_vector_type(4)));

#define TS16(v) (((((v)[0] + (v)[1]) + ((v)[2] + (v)[3])) + (((v)[4] + (v)[5]) + ((v)[6] + (v)[7]))) + \
                 ((((v)[8] + (v)[9]) + ((v)[10] + (v)[11])) + (((v)[12] + (v)[13]) + ((v)[14] + (v)[15]))))

// ---------------- f32 -> f16 convert + zero bkt_cnt + zero sentinel rows ----------------
__global__ void gnn_cvt(const float4* __restrict__ in, ushort4* __restrict__ out, int n4,
                        int* __restrict__ bkt_cnt, int nbkt,
                        __half* __restrict__ x16, __half* __restrict__ hA,
                        __half* __restrict__ hB, int N) {
    int i = blockIdx.x * blockDim.x + threadIdx.x;
    if (i < nbkt) bkt_cnt[i] = 0;
    if (i < 64) {  // zero sentinel row N of all three feature buffers
        x16[(size_t)N * 64 + i] = __ushort_as_half((unsigned short)0);
        hA[(size_t)N * 64 + i] = __ushort_as_half((unsigned short)0);
        hB[(size_t)N * 64 + i] = __ushort_as_half((unsigned short)0);
    }
    if (i < n4) {
        float4 f = in[i];
        ushort4 o;
        o.x = __half_as_ushort(__float2half(f.x));
        o.y = __half_as_ushort(__float2half(f.y));
        o.z = __half_as_ushort(__float2half(f.z));
        o.w = __half_as_ushort(__float2half(f.w));
        out[i] = o;
    }
}

// ---------------- bucket histogram (dst >> BSH), LDS-merged ----------------
__global__ __launch_bounds__(256) void gnn_bkt_hist(const int* __restrict__ dst,
                                                    int* __restrict__ bkt_cnt, int E, int nbkt) {
    __shared__ int h[512];
    for (int i = threadIdx.x; i < nbkt; i += 256) h[i] = 0;
    __syncthreads();
    int stride = gridDim.x * 256;
    for (int e = blockIdx.x * 256 + threadIdx.x; e < E; e += stride)
        atomicAdd(&h[dst[e] >> BSH], 1);
    __syncthreads();
    for (int i = threadIdx.x; i < nbkt; i += 256) {
        int v = h[i];
        if (v) atomicAdd(&bkt_cnt[i], v);
    }
}

// ---------------- bucket scan (1 wave) + zero gsum/gcnt (fused) ----------------
__global__ __launch_bounds__(256) void gnn_bkt_scan(const int* __restrict__ bkt_cnt,
                                                    int* __restrict__ bkt_base,
                                                    int* __restrict__ bkt_cur,
                                                    int* __restrict__ row_ptr,
                                                    float* __restrict__ gsum,
                                                    float* __restrict__ gcnt,
                                                    int nbkt, int N, int G) {
    int tid = threadIdx.x;
    for (int i = tid; i < G * 64; i += 256) gsum[i] = 0.0f;
    for (int i = tid; i < G; i += 256) gcnt[i] = 0.0f;
    if (tid < 64) {
        int lane = tid;
        int carry = 0;
        for (int base = 0; base < nbkt; base += 64) {
            int idx = base + lane;
            int v = (idx < nbkt) ? bkt_cnt[idx] : 0;
            int x = v;
#pragma unroll
            for (int off = 1; off < 64; off <<= 1) {
                int y = __shfl_up(x, off);
                if (lane >= off) x += y;
            }
            if (idx < nbkt) {
                bkt_base[idx] = carry + (x - v);
                bkt_cur[idx] = carry + (x - v);
            }
            carry += __shfl(x, 63);
        }
        if (lane == 0) {
            bkt_base[nbkt] = carry;
            row_ptr[N] = carry;
        }
    }
}

// ---------------- block-aggregated two-phase scatter (packed uint32) ----------------
__global__ __launch_bounds__(256) void gnn_bkt_scatter(const int* __restrict__ src,
                                                       const int* __restrict__ dst,
                                                       int* __restrict__ bkt_cur,
                                                       unsigned int* __restrict__ pairs,
                                                       int E, int nbkt) {
    __shared__ int hist[512];
    __shared__ int cur[512];
    int tid = threadIdx.x;
    int chunk = (E + gridDim.x - 1) / gridDim.x;
    int e0 = blockIdx.x * chunk;
    int e1 = min(E, e0 + chunk);
    for (int i = tid; i < nbkt; i += 256) hist[i] = 0;
    __syncthreads();
    for (int e = e0 + tid; e < e1; e += 256) atomicAdd(&hist[dst[e] >> BSH], 1);
    __syncthreads();
    for (int b = tid; b < nbkt; b += 256) {
        int c = hist[b];
        cur[b] = c ? atomicAdd(&bkt_cur[b], c) : 0;
    }
    __syncthreads();
    for (int e = e0 + tid; e < e1; e += 256) {
        int d = dst[e];
        int b = d >> BSH;
        int p = atomicAdd(&cur[b], 1);
        pairs[p] = (unsigned int)src[e] | ((unsigned int)(d & (BNODES - 1)) << 24);
    }
}

// ---------------- per-bucket CSR finalize ----------------
__global__ __launch_bounds__(256) void gnn_bkt_csr(const unsigned int* __restrict__ pairs,
                                                   const int* __restrict__ bkt_base,
                                                   int* __restrict__ row_ptr,
                                                   float* __restrict__ inv_deg,
                                                   int* __restrict__ csr_src, int N) {
    __shared__ int hist[BNODES];
    __shared__ int excl[BNODES];
    __shared__ int cur[BNODES];
    int b = blockIdx.x;
    int base = bkt_base[b];
    int cnt = bkt_base[b + 1] - base;
    int nd0 = b << BSH;
    int tid = threadIdx.x;
    hist[tid] = 0;
    __syncthreads();
    for (int i = tid; i < cnt; i += 256) atomicAdd(&hist[pairs[base + i] >> 24], 1);
    __syncthreads();
    if (tid < 64) {
        int carry = 0;
#pragma unroll
        for (int c = 0; c < BNODES; c += 64) {
            int v = hist[c + tid];
            int x = v;
#pragma unroll
            for (int off = 1; off < 64; off <<= 1) {
                int y = __shfl_up(x, off);
                if (tid >= off) x += y;
            }
            excl[c + tid] = carry + (x - v);
            carry += __shfl(x, 63);
        }
    }
    __syncthreads();
    {
        int node = nd0 + tid;
        if (node < N) {
            row_ptr[node] = base + excl[tid];
            int d = hist[tid];
            inv_deg[node] = 1.0f / (float)(d > 1 ? d : 1);
        }
        cur[tid] = excl[tid];
    }
    __syncthreads();
    for (int i = tid; i < cnt; i += 256) {
        unsigned int u = pairs[base + i];
        int j = u >> 24;
        int pos = atomicAdd(&cur[j], 1);
        csr_src[base + pos] = (int)(u & 0xFFFFFFu);
    }
}

// ---------------- fused SAGE layer (fp16, branchless-32 paired gather + MFMA) ----------------
// 8 waves/block share one weight copy (52.2 KB LDS -> 3 blocks/CU); one 16-node
// group per wave. Common case (deg<=32, 99.99% of nodes) is ONE basic block of
// 64 unconditioned loads (sentinel-padded) pipelined through 3 rotating buffers.
__global__ __launch_bounds__(512, 6) void gnn_sage(const __half* __restrict__ hin,
                                                   __half* __restrict__ hout,
                                                   const int* __restrict__ row_ptr,
                                                   const int* __restrict__ csr_src,
                                                   const float* __restrict__ inv_deg,
                                                   const float* __restrict__ Wl,
                                                   const float* __restrict__ bl,
                                                   const float* __restrict__ Wr, int n) {
    __shared__ _Float16 w_lds[64 * PADK];        // W2^T: [n][k], k = [Wl | Wr] (17408 B)
    __shared__ _Float16 in_lds[WPB][16 * PADK];  // per-wave [m][k] tile (4352 B each)
    int tid = threadIdx.x, lane = tid & 63, wv = tid >> 6;
    for (int i = tid; i < 64 * 64; i += 512) {
        int k = i >> 6, nn = i & 63;
        w_lds[nn * PADK + k] = (_Float16)Wl[i];
        w_lds[nn * PADK + 64 + k] = (_Float16)Wr[i];
    }
    __syncthreads();
    int ngroups = (n + 15) >> 4;
    int g = blockIdx.x * WPB + wv;
    if (g >= ngroups) return;
    int m16 = lane & 15, quad = lane >> 4;
    float bias[4];
#pragma unroll
    for (int nt = 0; nt < 4; nt++) bias[nt] = bl[nt * 16 + m16];
    _Float16* my_in = in_lds[wv];
    const _Float16* hin16 = (const _Float16*)hin;
    const __half* hrow = hin + lane;  // hoisted per-lane base
    int nd0 = g << 4;
    // ---- gather phase: 8 node-pairs, sentinel row n for padding ----
    for (int j2 = 0; j2 < 16; j2 += 2) {
        int ndA = min(nd0 + j2, n - 1);
        int ndB = min(nd0 + j2 + 1, n - 1);
        int s0A = row_ptr[ndA], s1A = row_ptr[ndA + 1];
        int s0B = row_ptr[ndB], s1B = row_ptr[ndB + 1];
        float idgA = inv_deg[ndA], idgB = inv_deg[ndB];
        // root rows -> K = 64..127
        my_in[j2 * PADK + 64 + lane] = hin16[(size_t)ndA * 64 + lane];
        my_in[(j2 + 1) * PADK + 64 + lane] = hin16[(size_t)ndB * 64 + lane];
        int cbA = s1A - s0A;
        int cbB = s1B - s0B;
        int eA = (lane < min(cbA, 64)) ? csr_src[s0A + lane] : n;  // n = zeroed sentinel
        int eB = (lane < min(cbB, 64)) ? csr_src[s0B + lane] : n;
        float accA, accB;
        {   // branchless common case: 32 edges per node, one BB, pipelined
            float v0[16], v1[16], v2[16];
#pragma unroll
            for (int j = 0; j < 16; j++) {
                int s = __shfl(eA, j);
                v0[j] = __half2float(hrow[(size_t)s * 64]);
            }
#pragma unroll
            for (int j = 0; j < 16; j++) {
                int s = __shfl(eB, j);
                v1[j] = __half2float(hrow[(size_t)s * 64]);
            }
#pragma unroll
            for (int j = 0; j < 16; j++) {
                int s = __shfl(eA, 16 + j);
                v2[j] = __half2float(hrow[(size_t)s * 64]);
            }
            accA = TS16(v0);
#pragma unroll
            for (int j = 0; j < 16; j++) {
                int s = __shfl(eB, 16 + j);
                v0[j] = __half2float(hrow[(size_t)s * 64]);
            }
            accB = TS16(v1);
            accA += TS16(v2);
            accB += TS16(v0);
        }
        // rare tail: deg > 32 (P ~ 1e-4)
        if (__builtin_expect(cbA > 32 || cbB > 32, 0)) {
#pragma unroll
            for (int ib = 2; ib < 4; ib++) {
                const int i0 = ib * 16;
                if (i0 < cbA) {
                    float v[16];
#pragma unroll
                    for (int j = 0; j < 16; j++) {
                        int s = __shfl(eA, i0 + j);
                        v[j] = __half2float(hrow[(size_t)s * 64]);
                    }
                    accA += TS16(v);
                }
                if (i0 < cbB) {
                    float v[16];
#pragma unroll
                    for (int j = 0; j < 16; j++) {
                        int s = __shfl(eB, i0 + j);
                        v[j] = __half2float(hrow[(size_t)s * 64]);
                    }
                    accB += TS16(v);
                }
            }
            for (int base = s0A + 64; base < s1A; base += 64) {
                int cb = min(64, s1A - base);
                int ei = (lane < cb) ? csr_src[base + lane] : n;
                for (int i0 = 0; i0 < cb; i0 += 16) {
                    float v[16];
#pragma unroll
                    for (int j = 0; j < 16; j++) {
                        int s = __shfl(ei, i0 + j);
                        v[j] = __half2float(hrow[(size_t)s * 64]);
                    }
                    accA += TS16(v);
                }
            }
            for (int base = s0B + 64; base < s1B; base += 64) {
                int cb = min(64, s1B - base);
                int ei = (lane < cb) ? csr_src[base + lane] : n;
                for (int i0 = 0; i0 < cb; i0 += 16) {
                    float v[16];
#pragma unroll
                    for (int j = 0; j < 16; j++) {
                        int s = __shfl(ei, i0 + j);
                        v[j] = __half2float(hrow[(size_t)s * 64]);
                    }
                    accB += TS16(v);
                }
            }
        }
        my_in[j2 * PADK + lane] = (_Float16)(accA * idgA);
        my_in[(j2 + 1) * PADK + lane] = (_Float16)(accB * idgB);
    }
    // ---- MFMA phase: D[16 nodes][64 feats] = A[16][128] * B[128][64] ----
    half8 afrag[4];
    const _Float16* abase = my_in + m16 * PADK + quad * 8;
#pragma unroll
    for (int ks = 0; ks < 4; ks++) afrag[ks] = *(const half8*)(abase + ks * 32);
    floatx4 accv[4];
#pragma unroll
    for (int nt = 0; nt < 4; nt++) {
        accv[nt].x = 0.f; accv[nt].y = 0.f; accv[nt].z = 0.f; accv[nt].w = 0.f;
    }
#pragma unroll
    for (int nt = 0; nt < 4; nt++) {
        const _Float16* bbase = w_lds + (nt * 16 + m16) * PADK + quad * 8;
#pragma unroll
        for (int ks = 0; ks < 4; ks++) {
            half8 bfrag = *(const half8*)(bbase + ks * 32);
            accv[nt] = __builtin_amdgcn_mfma_f32_16x16x32_f16(afrag[ks], bfrag, accv[nt], 0, 0, 0);
        }
    }
    // ---- epilogue: D col=lane&15 (feat), row=quad*4+reg (node) ----
#pragma unroll
    for (int nt = 0; nt < 4; nt++) {
#pragma unroll
        for (int r = 0; r < 4; r++) {
            int node = nd0 + quad * 4 + r;
            if (node < n) {
                float v = fmaxf(accv[nt][r] + bias[nt], 0.0f);
                hout[(size_t)node * 64 + nt * 16 + m16] = __float2half(v);
            }
        }
    }
}

// ---------------- global mean pool (batch is sorted, h is fp16) ----------------
__global__ __launch_bounds__(256) void gnn_pool(const __half* __restrict__ h,
                                                const int* __restrict__ batch,
                                                float* __restrict__ gsum,
                                                float* __restrict__ gcnt, int n) {
    int lane = threadIdx.x & 63, wv = threadIdx.x >> 6;
    int gw = blockIdx.x * 4 + wv;
    int start = gw * 64;
    if (start >= n) return;
    int cnt_here = min(64, n - start);
    int bi = start + lane;
    if (bi >= n) bi = n - 1;
    int myb = batch[bi];
    int b_first = __shfl(myb, 0);
    int b_last = __shfl(myb, cnt_here - 1);
    if (b_first == b_last && cnt_here == 64) {
        float a0 = 0, a1 = 0, a2 = 0, a3 = 0, a4 = 0, a5 = 0, a6 = 0, a7 = 0;
        const __half* p = h + (size_t)start * 64 + lane;
#pragma unroll
        for (int i = 0; i < 64; i += 8) {
            a0 += __half2float(p[(i + 0) * 64]);
            a1 += __half2float(p[(i + 1) * 64]);
            a2 += __half2float(p[(i + 2) * 64]);
            a3 += __half2float(p[(i + 3) * 64]);
            a4 += __half2float(p[(i + 4) * 64]);
            a5 += __half2float(p[(i + 5) * 64]);
            a6 += __half2float(p[(i + 6) * 64]);
            a7 += __half2float(p[(i + 7) * 64]);
        }
        float acc = ((a0 + a1) + (a2 + a3)) + ((a4 + a5) + (a6 + a7));
        atomicAdd(&gsum[b_first * 64 + lane], acc);
        if (lane == 0) atomicAdd(&gcnt[b_first], 64.0f);
        return;
    }
    float acc = 0.0f;
    int cnt = 0;
    int cur = b_first;
    for (int i = 0; i < cnt_here; i++) {
        int g = __shfl(myb, i);
        if (g != cur) {
            atomicAdd(&gsum[cur * 64 + lane], acc);
            if (lane == 0) atomicAdd(&gcnt[cur], (float)cnt);
            acc = 0.0f;
            cnt = 0;
            cur = g;
        }
        acc += __half2float(h[(size_t)(start + i) * 64 + lane]);
        cnt++;
    }
    atomicAdd(&gsum[cur * 64 + lane], acc);
    if (lane == 0) atomicAdd(&gcnt[cur], (float)cnt);
}

// ---------------- head ----------------
__global__ __launch_bounds__(256) void gnn_head(const float* __restrict__ gsum,
                                                const float* __restrict__ gcnt,
                                                const float* __restrict__ l0W,
                                                const float* __restrict__ l0b,
                                                const float* __restrict__ outW,
                                                const float* __restrict__ outb,
                                                float* __restrict__ out, int G, int OUT) {
    __shared__ float gm[64 * 64];
    __shared__ float t2[64 * 64];
    int tid = threadIdx.x;
    for (int i = tid; i < G * 64; i += 256) {
        int r = i >> 6;
        gm[i] = gsum[i] / fmaxf(gcnt[r], 1.0f);
    }
    __syncthreads();
    for (int i = tid; i < G * 64; i += 256) {
        int r = i >> 6, c = i & 63;
        float s = l0b[c];
#pragma unroll 8
        for (int k = 0; k < 64; k++) s += gm[(r << 6) + k] * l0W[(k << 6) + c];
        t2[i] = fmaxf(s, 0.0f);
    }
    __syncthreads();
    for (int i = tid; i < G * OUT; i += 256) {
        int r = i / OUT, c = i - r * OUT;
        float s = outb[c];
#pragma unroll 8
        for (int k = 0; k < 64; k++) s += t2[(r << 6) + k] * outW[k * OUT + c];
        out[i] = s;
    }
}

extern "C" void kernel_launch(void* const* d_in, const int* in_sizes, int n_in,
                              void* d_out, int out_size, void* d_ws, size_t ws_size,
                              hipStream_t stream) {
    const float* x = (const float*)d_in[0];
    const int* ei = (const int*)d_in[1];
    const int* batch = (const int*)d_in[2];
    const float* Wl[3] = {(const float*)d_in[3], (const float*)d_in[6], (const float*)d_in[9]};
    const float* bl[3] = {(const float*)d_in[4], (const float*)d_in[7], (const float*)d_in[10]};
    const float* Wr[3] = {(const float*)d_in[5], (const float*)d_in[8], (const float*)d_in[11]};
    const float* l0W = (const float*)d_in[12];
    const float* l0b = (const float*)d_in[13];
    const float* outW = (const float*)d_in[14];
    const float* outb = (const float*)d_in[15];

    int N = in_sizes[2];
    int E = in_sizes[1] / 2;
    int OUT = 10;
    int G = out_size / OUT;
    const int* src = ei;
    const int* dst = ei + E;
    int NBKT = (N + BNODES - 1) >> BSH;

    char* ws = (char*)d_ws;
    size_t off = 0;
    auto alloc = [&](size_t b) -> char* {
        char* p = ws + off;
        off = (off + b + 255) & ~(size_t)255;
        return p;
    };
    int* row_ptr = (int*)alloc((size_t)(N + 1) * 4);
    int* csr_src = (int*)alloc((size_t)E * 4);
    float* inv_deg = (float*)alloc((size_t)N * 4);
    int* bkt_cnt = (int*)alloc((size_t)NBKT * 4);
    int* bkt_base = (int*)alloc((size_t)(NBKT + 1) * 4);
    int* bkt_cur = (int*)alloc((size_t)NBKT * 4);
    unsigned int* pairs = (unsigned int*)alloc((size_t)E * 4);
    __half* x16 = (__half*)alloc((size_t)(N + 1) * 64 * 2);  // +1 sentinel row
    __half* hA = (__half*)alloc((size_t)(N + 1) * 64 * 2);
    __half* hB = (__half*)alloc((size_t)(N + 1) * 64 * 2);
    float* gsum = (float*)alloc((size_t)G * 64 * 4);
    float* gcnt = (float*)alloc((size_t)G * 4);

    int n4 = N * 64 / 4;
    gnn_cvt<<<(n4 + 255) / 256, 256, 0, stream>>>((const float4*)x, (ushort4*)x16, n4,
                                                  bkt_cnt, NBKT, x16, hA, hB, N);
    gnn_bkt_hist<<<256, 256, 0, stream>>>(dst, bkt_cnt, E, NBKT);
    gnn_bkt_scan<<<1, 256, 0, stream>>>(bkt_cnt, bkt_base, bkt_cur, row_ptr, gsum, gcnt,
                                        NBKT, N, G);
    gnn_bkt_scatter<<<SC_BLOCKS, 256, 0, stream>>>(src, dst, bkt_cur, pairs, E, NBKT);
    gnn_bkt_csr<<<NBKT, 256, 0, stream>>>(pairs, bkt_base, row_ptr, inv_deg, csr_src, N);

    int ngroups = (N + 15) >> 4;
    int sage_blocks = (ngroups + WPB - 1) / WPB;
    gnn_sage<<<sage_blocks, 512, 0, stream>>>(x16, hA, row_ptr, csr_src, inv_deg,
                                              Wl[0], bl[0], Wr[0], N);
    gnn_sage<<<sage_blocks, 512, 0, stream>>>(hA, hB, row_ptr, csr_src, inv_deg,
                                              Wl[1], bl[1], Wr[1], N);
    gnn_sage<<<sage_blocks, 512, 0, stream>>>(hB, hA, row_ptr, csr_src, inv_deg,
                                              Wl[2], bl[2], Wr[2], N);

    int pool_blocks = ((N + 63) / 64 + 3) / 4;
    gnn_pool<<<pool_blocks, 256, 0, stream>>>(hA, batch, gsum, gcnt, N);
    gnn_head<<<1, 256, 0, stream>>>(gsum, gcnt, l0W, l0b, outW, outb, (float*)d_out, G, OUT);
}

// Round 12
// 940.762 us; speedup vs baseline: 1.0232x; 1.0232x over previous
//
#include <hip/hip_runtime.h>
#include <hip/hip_fp16.h>

#define WPB 8     // waves per sage block (512 threads)
#define PADK 136  // f16 elems per LDS row: 128 + 8 pad (16B-aligned rows)
#define BSH 8     // bucket shift: 256 nodes per bucket
#define BNODES 256
#define SC_BLOCKS 256

typedef _Float16 half8 __attribute__((ext_vector_type(8)));
typedef float floatx4 __attribute__((ext_vector_type(4)));

#define TS16(v) (((((v)[0] + (v)[1]) + ((v)[2] + (v)[3])) + (((v)[4] + (v)[5]) + ((v)[6] + (v)[7]))) + \
                 ((((v)[8] + (v)[9]) + ((v)[10] + (v)[11])) + (((v)[12] + (v)[13]) + ((v)[14] + (v)[15]))))

// ---------------- f32 -> f16 convert + zero bkt_cnt + zero sentinel rows ----------------
__global__ void gnn_cvt(const float4* __restrict__ in, ushort4* __restrict__ out, int n4,
                        int* __restrict__ bkt_cnt, int nbkt,
                        __half* __restrict__ x16, __half* __restrict__ hA,
                        __half* __restrict__ hB, int N) {
    int i = blockIdx.x * blockDim.x + threadIdx.x;
    if (i < nbkt) bkt_cnt[i] = 0;
    if (i < 64) {  // zero sentinel row N of all three feature buffers
        x16[(size_t)N * 64 + i] = __ushort_as_half((unsigned short)0);
        hA[(size_t)N * 64 + i] = __ushort_as_half((unsigned short)0);
        hB[(size_t)N * 64 + i] = __ushort_as_half((unsigned short)0);
    }
    if (i < n4) {
        float4 f = in[i];
        ushort4 o;
        o.x = __half_as_ushort(__float2half(f.x));
        o.y = __half_as_ushort(__float2half(f.y));
        o.z = __half_as_ushort(__float2half(f.z));
        o.w = __half_as_ushort(__float2half(f.w));
        out[i] = o;
    }
}

// ---------------- bucket histogram (dst >> BSH), LDS-merged ----------------
__global__ __launch_bounds__(256) void gnn_bkt_hist(const int* __restrict__ dst,
                                                    int* __restrict__ bkt_cnt, int E, int nbkt) {
    __shared__ int h[512];
    for (int i = threadIdx.x; i < nbkt; i += 256) h[i] = 0;
    __syncthreads();
    int stride = gridDim.x * 256;
    for (int e = blockIdx.x * 256 + threadIdx.x; e < E; e += stride)
        atomicAdd(&h[dst[e] >> BSH], 1);
    __syncthreads();
    for (int i = threadIdx.x; i < nbkt; i += 256) {
        int v = h[i];
        if (v) atomicAdd(&bkt_cnt[i], v);
    }
}

// ---------------- bucket scan (1 wave) + zero gsum/gcnt (fused) ----------------
__global__ __launch_bounds__(256) void gnn_bkt_scan(const int* __restrict__ bkt_cnt,
                                                    int* __restrict__ bkt_base,
                                                    int* __restrict__ bkt_cur,
                                                    int* __restrict__ row_ptr,
                                                    float* __restrict__ gsum,
                                                    float* __restrict__ gcnt,
                                                    int nbkt, int N, int G) {
    int tid = threadIdx.x;
    for (int i = tid; i < G * 64; i += 256) gsum[i] = 0.0f;
    for (int i = tid; i < G; i += 256) gcnt[i] = 0.0f;
    if (tid < 64) {
        int lane = tid;
        int carry = 0;
        for (int base = 0; base < nbkt; base += 64) {
            int idx = base + lane;
            int v = (idx < nbkt) ? bkt_cnt[idx] : 0;
            int x = v;
#pragma unroll
            for (int off = 1; off < 64; off <<= 1) {
                int y = __shfl_up(x, off);
                if (lane >= off) x += y;
            }
            if (idx < nbkt) {
                bkt_base[idx] = carry + (x - v);
                bkt_cur[idx] = carry + (x - v);
            }
            carry += __shfl(x, 63);
        }
        if (lane == 0) {
            bkt_base[nbkt] = carry;
            row_ptr[N] = carry;
        }
    }
}

// ---------------- block-aggregated two-phase scatter (packed uint32) ----------------
__global__ __launch_bounds__(256) void gnn_bkt_scatter(const int* __restrict__ src,
                                                       const int* __restrict__ dst,
                                                       int* __restrict__ bkt_cur,
                                                       unsigned int* __restrict__ pairs,
                                                       int E, int nbkt) {
    __shared__ int hist[512];
    __shared__ int cur[512];
    int tid = threadIdx.x;
    int chunk = (E + gridDim.x - 1) / gridDim.x;
    int e0 = blockIdx.x * chunk;
    int e1 = min(E, e0 + chunk);
    for (int i = tid; i < nbkt; i += 256) hist[i] = 0;
    __syncthreads();
    for (int e = e0 + tid; e < e1; e += 256) atomicAdd(&hist[dst[e] >> BSH], 1);
    __syncthreads();
    for (int b = tid; b < nbkt; b += 256) {
        int c = hist[b];
        cur[b] = c ? atomicAdd(&bkt_cur[b], c) : 0;
    }
    __syncthreads();
    for (int e = e0 + tid; e < e1; e += 256) {
        int d = dst[e];
        int b = d >> BSH;
        int p = atomicAdd(&cur[b], 1);
        pairs[p] = (unsigned int)src[e] | ((unsigned int)(d & (BNODES - 1)) << 24);
    }
}

// ---------------- per-bucket CSR finalize ----------------
__global__ __launch_bounds__(256) void gnn_bkt_csr(const unsigned int* __restrict__ pairs,
                                                   const int* __restrict__ bkt_base,
                                                   int* __restrict__ row_ptr,
                                                   float* __restrict__ inv_deg,
                                                   int* __restrict__ csr_src, int N) {
    __shared__ int hist[BNODES];
    __shared__ int excl[BNODES];
    __shared__ int cur[BNODES];
    int b = blockIdx.x;
    int base = bkt_base[b];
    int cnt = bkt_base[b + 1] - base;
    int nd0 = b << BSH;
    int tid = threadIdx.x;
    hist[tid] = 0;
    __syncthreads();
    for (int i = tid; i < cnt; i += 256) atomicAdd(&hist[pairs[base + i] >> 24], 1);
    __syncthreads();
    if (tid < 64) {
        int carry = 0;
#pragma unroll
        for (int c = 0; c < BNODES; c += 64) {
            int v = hist[c + tid];
            int x = v;
#pragma unroll
            for (int off = 1; off < 64; off <<= 1) {
                int y = __shfl_up(x, off);
                if (tid >= off) x += y;
            }
            excl[c + tid] = carry + (x - v);
            carry += __shfl(x, 63);
        }
    }
    __syncthreads();
    {
        int node = nd0 + tid;
        if (node < N) {
            row_ptr[node] = base + excl[tid];
            int d = hist[tid];
            inv_deg[node] = 1.0f / (float)(d > 1 ? d : 1);
        }
        cur[tid] = excl[tid];
    }
    __syncthreads();
    for (int i = tid; i < cnt; i += 256) {
        unsigned int u = pairs[base + i];
        int j = u >> 24;
        int pos = atomicAdd(&cur[j], 1);
        csr_src[base + pos] = (int)(u & 0xFFFFFFu);
    }
}

// ---------------- fused SAGE layer (fp16, 2-buffer interleaved gather + MFMA) ----------------
// 8 waves/block share one weight copy (52.2 KB LDS -> 3 blocks/CU); one 16-node
// group per wave. Gather: first 16 edges of node A + first 16 of node B in ONE
// basic block (32 outstanding loads, 2x16 buffers -> no spill at 85-VGPR cap);
// edges 16..32 in one shared guarded block; deg>32 rare tail.
__global__ __launch_bounds__(512, 6) void gnn_sage(const __half* __restrict__ hin,
                                                   __half* __restrict__ hout,
                                                   const int* __restrict__ row_ptr,
                                                   const int* __restrict__ csr_src,
                                                   const float* __restrict__ inv_deg,
                                                   const float* __restrict__ Wl,
                                                   const float* __restrict__ bl,
                                                   const float* __restrict__ Wr, int n) {
    __shared__ _Float16 w_lds[64 * PADK];        // W2^T: [n][k], k = [Wl | Wr] (17408 B)
    __shared__ _Float16 in_lds[WPB][16 * PADK];  // per-wave [m][k] tile (4352 B each)
    int tid = threadIdx.x, lane = tid & 63, wv = tid >> 6;
    for (int i = tid; i < 64 * 64; i += 512) {
        int k = i >> 6, nn = i & 63;
        w_lds[nn * PADK + k] = (_Float16)Wl[i];
        w_lds[nn * PADK + 64 + k] = (_Float16)Wr[i];
    }
    __syncthreads();
    int ngroups = (n + 15) >> 4;
    int g = blockIdx.x * WPB + wv;
    if (g >= ngroups) return;
    int m16 = lane & 15, quad = lane >> 4;
    float bias[4];
#pragma unroll
    for (int nt = 0; nt < 4; nt++) bias[nt] = bl[nt * 16 + m16];
    _Float16* my_in = in_lds[wv];
    const _Float16* hin16 = (const _Float16*)hin;
    const __half* hrow = hin + lane;  // hoisted per-lane base
    int nd0 = g << 4;
    // ---- gather phase: 8 node-pairs, sentinel row n for padding ----
    for (int j2 = 0; j2 < 16; j2 += 2) {
        int ndA = min(nd0 + j2, n - 1);
        int ndB = min(nd0 + j2 + 1, n - 1);
        int s0A = row_ptr[ndA], s1A = row_ptr[ndA + 1];
        int s0B = row_ptr[ndB], s1B = row_ptr[ndB + 1];
        float idgA = inv_deg[ndA], idgB = inv_deg[ndB];
        // root rows -> K = 64..127
        my_in[j2 * PADK + 64 + lane] = hin16[(size_t)ndA * 64 + lane];
        my_in[(j2 + 1) * PADK + 64 + lane] = hin16[(size_t)ndB * 64 + lane];
        int cbA = s1A - s0A;
        int cbB = s1B - s0B;
        int eA = (lane < min(cbA, 64)) ? csr_src[s0A + lane] : n;  // n = zeroed sentinel
        int eB = (lane < min(cbB, 64)) ? csr_src[s0B + lane] : n;
        float accA, accB;
        {   // common case BB: 16+16 interleaved unconditional loads (sentinel-padded)
            float vA[16], vB[16];
#pragma unroll
            for (int j = 0; j < 16; j++) {
                int s = __shfl(eA, j);
                vA[j] = __half2float(hrow[(size_t)s * 64]);
            }
#pragma unroll
            for (int j = 0; j < 16; j++) {
                int s = __shfl(eB, j);
                vB[j] = __half2float(hrow[(size_t)s * 64]);
            }
            accA = TS16(vA);
            accB = TS16(vB);
        }
        if (cbA > 16 || cbB > 16) {  // edges 16..32, both sentinel-padded
            float vA[16], vB[16];
#pragma unroll
            for (int j = 0; j < 16; j++) {
                int s = __shfl(eA, 16 + j);
                vA[j] = __half2float(hrow[(size_t)s * 64]);
            }
#pragma unroll
            for (int j = 0; j < 16; j++) {
                int s = __shfl(eB, 16 + j);
                vB[j] = __half2float(hrow[(size_t)s * 64]);
            }
            accA += TS16(vA);
            accB += TS16(vB);
            // rare tail: deg > 32 (P ~ 1e-4)
            if (__builtin_expect(cbA > 32 || cbB > 32, 0)) {
#pragma unroll
                for (int ib = 2; ib < 4; ib++) {
                    const int i0 = ib * 16;
                    if (i0 < cbA) {
                        float v[16];
#pragma unroll
                        for (int j = 0; j < 16; j++) {
                            int s = __shfl(eA, i0 + j);
                            v[j] = __half2float(hrow[(size_t)s * 64]);
                        }
                        accA += TS16(v);
                    }
                    if (i0 < cbB) {
                        float v[16];
#pragma unroll
                        for (int j = 0; j < 16; j++) {
                            int s = __shfl(eB, i0 + j);
                            v[j] = __half2float(hrow[(size_t)s * 64]);
                        }
                        accB += TS16(v);
                    }
                }
                for (int base = s0A + 64; base < s1A; base += 64) {
                    int cb = min(64, s1A - base);
                    int ei = (lane < cb) ? csr_src[base + lane] : n;
                    for (int i0 = 0; i0 < cb; i0 += 16) {
                        float v[16];
#pragma unroll
                        for (int j = 0; j < 16; j++) {
                            int s = __shfl(ei, i0 + j);
                            v[j] = __half2float(hrow[(size_t)s * 64]);
                        }
                        accA += TS16(v);
                    }
                }
                for (int base = s0B + 64; base < s1B; base += 64) {
                    int cb = min(64, s1B - base);
                    int ei = (lane < cb) ? csr_src[base + lane] : n;
                    for (int i0 = 0; i0 < cb; i0 += 16) {
                        float v[16];
#pragma unroll
                        for (int j = 0; j < 16; j++) {
                            int s = __shfl(ei, i0 + j);
                            v[j] = __half2float(hrow[(size_t)s * 64]);
                        }
                        accB += TS16(v);
                    }
                }
            }
        }
        my_in[j2 * PADK + lane] = (_Float16)(accA * idgA);
        my_in[(j2 + 1) * PADK + lane] = (_Float16)(accB * idgB);
    }
    // ---- MFMA phase: D[16 nodes][64 feats] = A[16][128] * B[128][64] ----
    half8 afrag[4];
    const _Float16* abase = my_in + m16 * PADK + quad * 8;
#pragma unroll
    for (int ks = 0; ks < 4; ks++) afrag[ks] = *(const half8*)(abase + ks * 32);
    floatx4 accv[4];
#pragma unroll
    for (int nt = 0; nt < 4; nt++) {
        accv[nt].x = 0.f; accv[nt].y = 0.f; accv[nt].z = 0.f; accv[nt].w = 0.f;
    }
#pragma unroll
    for (int nt = 0; nt < 4; nt++) {
        const _Float16* bbase = w_lds + (nt * 16 + m16) * PADK + quad * 8;
#pragma unroll
        for (int ks = 0; ks < 4; ks++) {
            half8 bfrag = *(const half8*)(bbase + ks * 32);
            accv[nt] = __builtin_amdgcn_mfma_f32_16x16x32_f16(afrag[ks], bfrag, accv[nt], 0, 0, 0);
        }
    }
    // ---- epilogue: D col=lane&15 (feat), row=quad*4+reg (node) ----
#pragma unroll
    for (int nt = 0; nt < 4; nt++) {
#pragma unroll
        for (int r = 0; r < 4; r++) {
            int node = nd0 + quad * 4 + r;
            if (node < n) {
                float v = fmaxf(accv[nt][r] + bias[nt], 0.0f);
                hout[(size_t)node * 64 + nt * 16 + m16] = __float2half(v);
            }
        }
    }
}

// ---------------- global mean pool (batch is sorted, h is fp16) ----------------
__global__ __launch_bounds__(256) void gnn_pool(const __half* __restrict__ h,
                                                const int* __restrict__ batch,
                                                float* __restrict__ gsum,
                                                float* __restrict__ gcnt, int n) {
    int lane = threadIdx.x & 63, wv = threadIdx.x >> 6;
    int gw = blockIdx.x * 4 + wv;
    int start = gw * 64;
    if (start >= n) return;
    int cnt_here = min(64, n - start);
    int bi = start + lane;
    if (bi >= n) bi = n - 1;
    int myb = batch[bi];
    int b_first = __shfl(myb, 0);
    int b_last = __shfl(myb, cnt_here - 1);
    if (b_first == b_last && cnt_here == 64) {
        float a0 = 0, a1 = 0, a2 = 0, a3 = 0, a4 = 0, a5 = 0, a6 = 0, a7 = 0;
        const __half* p = h + (size_t)start * 64 + lane;
#pragma unroll
        for (int i = 0; i < 64; i += 8) {
            a0 += __half2float(p[(i + 0) * 64]);
            a1 += __half2float(p[(i + 1) * 64]);
            a2 += __half2float(p[(i + 2) * 64]);
            a3 += __half2float(p[(i + 3) * 64]);
            a4 += __half2float(p[(i + 4) * 64]);
            a5 += __half2float(p[(i + 5) * 64]);
            a6 += __half2float(p[(i + 6) * 64]);
            a7 += __half2float(p[(i + 7) * 64]);
        }
        float acc = ((a0 + a1) + (a2 + a3)) + ((a4 + a5) + (a6 + a7));
        atomicAdd(&gsum[b_first * 64 + lane], acc);
        if (lane == 0) atomicAdd(&gcnt[b_first], 64.0f);
        return;
    }
    float acc = 0.0f;
    int cnt = 0;
    int cur = b_first;
    for (int i = 0; i < cnt_here; i++) {
        int g = __shfl(myb, i);
        if (g != cur) {
            atomicAdd(&gsum[cur * 64 + lane], acc);
            if (lane == 0) atomicAdd(&gcnt[cur], (float)cnt);
            acc = 0.0f;
            cnt = 0;
            cur = g;
        }
        acc += __half2float(h[(size_t)(start + i) * 64 + lane]);
        cnt++;
    }
    atomicAdd(&gsum[cur * 64 + lane], acc);
    if (lane == 0) atomicAdd(&gcnt[cur], (float)cnt);
}

// ---------------- head ----------------
__global__ __launch_bounds__(256) void gnn_head(const float* __restrict__ gsum,
                                                const float* __restrict__ gcnt,
                                                const float* __restrict__ l0W,
                                                const float* __restrict__ l0b,
                                                const float* __restrict__ outW,
                                                const float* __restrict__ outb,
                                                float* __restrict__ out, int G, int OUT) {
    __shared__ float gm[64 * 64];
    __shared__ float t2[64 * 64];
    int tid = threadIdx.x;
    for (int i = tid; i < G * 64; i += 256) {
        int r = i >> 6;
        gm[i] = gsum[i] / fmaxf(gcnt[r], 1.0f);
    }
    __syncthreads();
    for (int i = tid; i < G * 64; i += 256) {
        int r = i >> 6, c = i & 63;
        float s = l0b[c];
#pragma unroll 8
        for (int k = 0; k < 64; k++) s += gm[(r << 6) + k] * l0W[(k << 6) + c];
        t2[i] = fmaxf(s, 0.0f);
    }
    __syncthreads();
    for (int i = tid; i < G * OUT; i += 256) {
        int r = i / OUT, c = i - r * OUT;
        float s = outb[c];
#pragma unroll 8
        for (int k = 0; k < 64; k++) s += t2[(r << 6) + k] * outW[k * OUT + c];
        out[i] = s;
    }
}

extern "C" void kernel_launch(void* const* d_in, const int* in_sizes, int n_in,
                              void* d_out, int out_size, void* d_ws, size_t ws_size,
                              hipStream_t stream) {
    const float* x = (const float*)d_in[0];
    const int* ei = (const int*)d_in[1];
    const int* batch = (const int*)d_in[2];
    const float* Wl[3] = {(const float*)d_in[3], (const float*)d_in[6], (const float*)d_in[9]};
    const float* bl[3] = {(const float*)d_in[4], (const float*)d_in[7], (const float*)d_in[10]};
    const float* Wr[3] = {(const float*)d_in[5], (const float*)d_in[8], (const float*)d_in[11]};
    const float* l0W = (const float*)d_in[12];
    const float* l0b = (const float*)d_in[13];
    const float* outW = (const float*)d_in[14];
    const float* outb = (const float*)d_in[15];

    int N = in_sizes[2];
    int E = in_sizes[1] / 2;
    int OUT = 10;
    int G = out_size / OUT;
    const int* src = ei;
    const int* dst = ei + E;
    int NBKT = (N + BNODES - 1) >> BSH;

    char* ws = (char*)d_ws;
    size_t off = 0;
    auto alloc = [&](size_t b) -> char* {
        char* p = ws + off;
        off = (off + b + 255) & ~(size_t)255;
        return p;
    };
    int* row_ptr = (int*)alloc((size_t)(N + 1) * 4);
    int* csr_src = (int*)alloc((size_t)E * 4);
    float* inv_deg = (float*)alloc((size_t)N * 4);
    int* bkt_cnt = (int*)alloc((size_t)NBKT * 4);
    int* bkt_base = (int*)alloc((size_t)(NBKT + 1) * 4);
    int* bkt_cur = (int*)alloc((size_t)NBKT * 4);
    unsigned int* pairs = (unsigned int*)alloc((size_t)E * 4);
    __half* x16 = (__half*)alloc((size_t)(N + 1) * 64 * 2);  // +1 sentinel row
    __half* hA = (__half*)alloc((size_t)(N + 1) * 64 * 2);
    __half* hB = (__half*)alloc((size_t)(N + 1) * 64 * 2);
    float* gsum = (float*)alloc((size_t)G * 64 * 4);
    float* gcnt = (float*)alloc((size_t)G * 4);

    int n4 = N * 64 / 4;
    gnn_cvt<<<(n4 + 255) / 256, 256, 0, stream>>>((const float4*)x, (ushort4*)x16, n4,
                                                  bkt_cnt, NBKT, x16, hA, hB, N);
    gnn_bkt_hist<<<256, 256, 0, stream>>>(dst, bkt_cnt, E, NBKT);
    gnn_bkt_scan<<<1, 256, 0, stream>>>(bkt_cnt, bkt_base, bkt_cur, row_ptr, gsum, gcnt,
                                        NBKT, N, G);
    gnn_bkt_scatter<<<SC_BLOCKS, 256, 0, stream>>>(src, dst, bkt_cur, pairs, E, NBKT);
    gnn_bkt_csr<<<NBKT, 256, 0, stream>>>(pairs, bkt_base, row_ptr, inv_deg, csr_src, N);

    int ngroups = (N + 15) >> 4;
    int sage_blocks = (ngroups + WPB - 1) / WPB;
    gnn_sage<<<sage_blocks, 512, 0, stream>>>(x16, hA, row_ptr, csr_src, inv_deg,
                                              Wl[0], bl[0], Wr[0], N);
    gnn_sage<<<sage_blocks, 512, 0, stream>>>(hA, hB, row_ptr, csr_src, inv_deg,
                                              Wl[1], bl[1], Wr[1], N);
    gnn_sage<<<sage_blocks, 512, 0, stream>>>(hB, hA, row_ptr, csr_src, inv_deg,
                                              Wl[2], bl[2], Wr[2], N);

    int pool_blocks = ((N + 63) / 64 + 3) / 4;
    gnn_pool<<<pool_blocks, 256, 0, stream>>>(hA, batch, gsum, gcnt, N);
    gnn_head<<<1, 256, 0, stream>>>(gsum, gcnt, l0W, l0b, outW, outb, (float*)d_out, G, OUT);
}

// Round 13
// 447.570 us; speedup vs baseline: 2.1507x; 2.1019x over previous
//
#include <hip/hip_runtime.h>
#include <hip/hip_fp16.h>

#define WPB 8     // waves per sage block (512 threads)
#define PADK 136  // f16 elems per LDS row: 128 + 8 pad (16B-aligned rows)
#define BSH 8     // bucket shift: 256 nodes per bucket
#define BNODES 256
#define SC_BLOCKS 256
#define HIST_BLOCKS 256

typedef _Float16 half8 __attribute__((ext_vector_type(8)));
typedef float floatx4 __attribute__((ext_vector_type(4)));

#define TS16(v) (((((v)[0] + (v)[1]) + ((v)[2] + (v)[3])) + (((v)[4] + (v)[5]) + ((v)[6] + (v)[7]))) + \
                 ((((v)[8] + (v)[9]) + ((v)[10] + (v)[11])) + (((v)[12] + (v)[13]) + ((v)[14] + (v)[15]))))

// ---------------- fused: bucket histogram (blocks 0..255) + f32->f16 convert (rest) ----------------
__global__ __launch_bounds__(256) void gnn_cvt_hist(const float4* __restrict__ in,
                                                    ushort4* __restrict__ out, int n4,
                                                    const int* __restrict__ dst,
                                                    int* __restrict__ bkt_cnt, int nbkt, int E,
                                                    __half* __restrict__ x16,
                                                    __half* __restrict__ hA,
                                                    __half* __restrict__ hB, int N) {
    if (blockIdx.x < HIST_BLOCKS) {
        __shared__ int h[512];
        for (int i = threadIdx.x; i < nbkt; i += 256) h[i] = 0;
        __syncthreads();
        const int stride = HIST_BLOCKS * 256;
        for (int e = blockIdx.x * 256 + threadIdx.x; e < E; e += stride)
            atomicAdd(&h[dst[e] >> BSH], 1);
        __syncthreads();
        for (int i = threadIdx.x; i < nbkt; i += 256) {
            int v = h[i];
            if (v) atomicAdd(&bkt_cnt[i], v);
        }
        return;
    }
    int i = (blockIdx.x - HIST_BLOCKS) * 256 + threadIdx.x;
    if (i < 64) {  // zero sentinel row N of all three feature buffers
        x16[(size_t)N * 64 + i] = __ushort_as_half((unsigned short)0);
        hA[(size_t)N * 64 + i] = __ushort_as_half((unsigned short)0);
        hB[(size_t)N * 64 + i] = __ushort_as_half((unsigned short)0);
    }
    if (i < n4) {
        float4 f = in[i];
        ushort4 o;
        o.x = __half_as_ushort(__float2half(f.x));
        o.y = __half_as_ushort(__float2half(f.y));
        o.z = __half_as_ushort(__float2half(f.z));
        o.w = __half_as_ushort(__float2half(f.w));
        out[i] = o;
    }
}

// ---------------- bucket scan (1 wave) + zero gsum/gcnt (fused) ----------------
__global__ __launch_bounds__(256) void gnn_bkt_scan(const int* __restrict__ bkt_cnt,
                                                    int* __restrict__ bkt_base,
                                                    int* __restrict__ bkt_cur,
                                                    int* __restrict__ row_ptr,
                                                    float* __restrict__ gsum,
                                                    float* __restrict__ gcnt,
                                                    int nbkt, int N, int G) {
    int tid = threadIdx.x;
    for (int i = tid; i < G * 64; i += 256) gsum[i] = 0.0f;
    for (int i = tid; i < G; i += 256) gcnt[i] = 0.0f;
    if (tid < 64) {
        int lane = tid;
        int carry = 0;
        for (int base = 0; base < nbkt; base += 64) {
            int idx = base + lane;
            int v = (idx < nbkt) ? bkt_cnt[idx] : 0;
            int x = v;
#pragma unroll
            for (int off = 1; off < 64; off <<= 1) {
                int y = __shfl_up(x, off);
                if (lane >= off) x += y;
            }
            if (idx < nbkt) {
                bkt_base[idx] = carry + (x - v);
                bkt_cur[idx] = carry + (x - v);
            }
            carry += __shfl(x, 63);
        }
        if (lane == 0) {
            bkt_base[nbkt] = carry;
            row_ptr[N] = carry;
        }
    }
}

// ---------------- block-aggregated two-phase scatter (packed uint32) ----------------
__global__ __launch_bounds__(256) void gnn_bkt_scatter(const int* __restrict__ src,
                                                       const int* __restrict__ dst,
                                                       int* __restrict__ bkt_cur,
                                                       unsigned int* __restrict__ pairs,
                                                       int E, int nbkt) {
    __shared__ int hist[512];
    __shared__ int cur[512];
    int tid = threadIdx.x;
    int chunk = (E + gridDim.x - 1) / gridDim.x;
    int e0 = blockIdx.x * chunk;
    int e1 = min(E, e0 + chunk);
    for (int i = tid; i < nbkt; i += 256) hist[i] = 0;
    __syncthreads();
    for (int e = e0 + tid; e < e1; e += 256) atomicAdd(&hist[dst[e] >> BSH], 1);
    __syncthreads();
    for (int b = tid; b < nbkt; b += 256) {
        int c = hist[b];
        cur[b] = c ? atomicAdd(&bkt_cur[b], c) : 0;
    }
    __syncthreads();
    for (int e = e0 + tid; e < e1; e += 256) {
        int d = dst[e];
        int b = d >> BSH;
        int p = atomicAdd(&cur[b], 1);
        pairs[p] = (unsigned int)src[e] | ((unsigned int)(d & (BNODES - 1)) << 24);
    }
}

// ---------------- per-bucket CSR finalize ----------------
__global__ __launch_bounds__(256) void gnn_bkt_csr(const unsigned int* __restrict__ pairs,
                                                   const int* __restrict__ bkt_base,
                                                   int* __restrict__ row_ptr,
                                                   float* __restrict__ inv_deg,
                                                   int* __restrict__ csr_src, int N) {
    __shared__ int hist[BNODES];
    __shared__ int excl[BNODES];
    __shared__ int cur[BNODES];
    int b = blockIdx.x;
    int base = bkt_base[b];
    int cnt = bkt_base[b + 1] - base;
    int nd0 = b << BSH;
    int tid = threadIdx.x;
    hist[tid] = 0;
    __syncthreads();
    for (int i = tid; i < cnt; i += 256) atomicAdd(&hist[pairs[base + i] >> 24], 1);
    __syncthreads();
    if (tid < 64) {
        int carry = 0;
#pragma unroll
        for (int c = 0; c < BNODES; c += 64) {
            int v = hist[c + tid];
            int x = v;
#pragma unroll
            for (int off = 1; off < 64; off <<= 1) {
                int y = __shfl_up(x, off);
                if (tid >= off) x += y;
            }
            excl[c + tid] = carry + (x - v);
            carry += __shfl(x, 63);
        }
    }
    __syncthreads();
    {
        int node = nd0 + tid;
        if (node < N) {
            row_ptr[node] = base + excl[tid];
            int d = hist[tid];
            inv_deg[node] = 1.0f / (float)(d > 1 ? d : 1);
        }
        cur[tid] = excl[tid];
    }
    __syncthreads();
    for (int i = tid; i < cnt; i += 256) {
        unsigned int u = pairs[base + i];
        int j = u >> 24;
        int pos = atomicAdd(&cur[j], 1);
        csr_src[base + pos] = (int)(u & 0xFFFFFFu);
    }
}

// ---------------- fused SAGE layer (R10 structure: paired guarded-16 gather + MFMA) ----------------
// 8 waves/block share one weight copy (52.2 KB -> 3 blocks/CU); one 16-node group
// per wave; cooperative row_ptr/inv_deg load (lane-parallel + shfl) kills 48
// wave-uniform VMEM issues per group. N % 16 == 0 so no node clamping needed.
__global__ __launch_bounds__(512, 6) void gnn_sage(const __half* __restrict__ hin,
                                                   __half* __restrict__ hout,
                                                   const int* __restrict__ row_ptr,
                                                   const int* __restrict__ csr_src,
                                                   const float* __restrict__ inv_deg,
                                                   const float* __restrict__ Wl,
                                                   const float* __restrict__ bl,
                                                   const float* __restrict__ Wr, int n) {
    __shared__ _Float16 w_lds[64 * PADK];        // W2^T: [n][k], k = [Wl | Wr] (17408 B)
    __shared__ _Float16 in_lds[WPB][16 * PADK];  // per-wave [m][k] tile (4352 B each)
    int tid = threadIdx.x, lane = tid & 63, wv = tid >> 6;
    for (int i = tid; i < 64 * 64; i += 512) {
        int k = i >> 6, nn = i & 63;
        w_lds[nn * PADK + k] = (_Float16)Wl[i];
        w_lds[nn * PADK + 64 + k] = (_Float16)Wr[i];
    }
    __syncthreads();
    int ngroups = (n + 15) >> 4;
    int g = blockIdx.x * WPB + wv;
    if (g >= ngroups) return;
    int m16 = lane & 15, quad = lane >> 4;
    float bias[4];
#pragma unroll
    for (int nt = 0; nt < 4; nt++) bias[nt] = bl[nt * 16 + m16];
    _Float16* my_in = in_lds[wv];
    const _Float16* hin16 = (const _Float16*)hin;
    int nd0 = g << 4;
    // cooperative metadata load: 17 row_ptr + 16 inv_deg, one lane-parallel issue each
    int rp = (lane < 17) ? row_ptr[nd0 + lane] : 0;
    float idgl = (lane < 16) ? inv_deg[nd0 + lane] : 0.0f;
    // ---- gather phase: 8 node-pairs (R10-proven guarded 16-batches) ----
    for (int j2 = 0; j2 < 16; j2 += 2) {
        int ndA = nd0 + j2;
        int ndB = nd0 + j2 + 1;
        int s0A = __shfl(rp, j2);
        int s1A = __shfl(rp, j2 + 1);
        int s1B = __shfl(rp, j2 + 2);
        int s0B = s1A;
        float idgA = __shfl(idgl, j2), idgB = __shfl(idgl, j2 + 1);
        // root rows -> K = 64..127
        my_in[j2 * PADK + 64 + lane] = hin16[(size_t)ndA * 64 + lane];
        my_in[(j2 + 1) * PADK + 64 + lane] = hin16[(size_t)ndB * 64 + lane];
        float accA = 0.0f, accB = 0.0f;
        int cbA = min(64, s1A - s0A);
        int cbB = min(64, s1B - s0B);
        int eA = (lane < cbA) ? csr_src[s0A + lane] : n;  // n = zeroed sentinel row
        int eB = (lane < cbB) ? csr_src[s0B + lane] : n;
#pragma unroll
        for (int ib = 0; ib < 4; ib++) {
            const int i0 = ib * 16;
            if (i0 < cbA) {
                float vA[16];
#pragma unroll
                for (int j = 0; j < 16; j++) {
                    int sj = __shfl(eA, i0 + j);
                    vA[j] = __half2float(hin[(size_t)sj * 64 + lane]);
                }
                accA += TS16(vA);
            }
            if (i0 < cbB) {
                float vB[16];
#pragma unroll
                for (int j = 0; j < 16; j++) {
                    int sj = __shfl(eB, i0 + j);
                    vB[j] = __half2float(hin[(size_t)sj * 64 + lane]);
                }
                accB += TS16(vB);
            }
        }
        // rare tails (deg > 64)
        for (int base = s0A + 64; base < s1A; base += 64) {
            int cb = min(64, s1A - base);
            int ei = (lane < cb) ? csr_src[base + lane] : n;
            for (int i0 = 0; i0 < cb; i0 += 16) {
                float v[16];
#pragma unroll
                for (int j = 0; j < 16; j++) {
                    int s = __shfl(ei, i0 + j);
                    v[j] = __half2float(hin[(size_t)s * 64 + lane]);
                }
                accA += TS16(v);
            }
        }
        for (int base = s0B + 64; base < s1B; base += 64) {
            int cb = min(64, s1B - base);
            int ei = (lane < cb) ? csr_src[base + lane] : n;
            for (int i0 = 0; i0 < cb; i0 += 16) {
                float v[16];
#pragma unroll
                for (int j = 0; j < 16; j++) {
                    int s = __shfl(ei, i0 + j);
                    v[j] = __half2float(hin[(size_t)s * 64 + lane]);
                }
                accB += TS16(v);
            }
        }
        my_in[j2 * PADK + lane] = (_Float16)(accA * idgA);
        my_in[(j2 + 1) * PADK + lane] = (_Float16)(accB * idgB);
    }
    // ---- MFMA phase: D[16 nodes][64 feats] = A[16][128] * B[128][64] ----
    half8 afrag[4];
    const _Float16* abase = my_in + m16 * PADK + quad * 8;
#pragma unroll
    for (int ks = 0; ks < 4; ks++) afrag[ks] = *(const half8*)(abase + ks * 32);
    floatx4 accv[4];
#pragma unroll
    for (int nt = 0; nt < 4; nt++) {
        accv[nt].x = 0.f; accv[nt].y = 0.f; accv[nt].z = 0.f; accv[nt].w = 0.f;
    }
#pragma unroll
    for (int nt = 0; nt < 4; nt++) {
        const _Float16* bbase = w_lds + (nt * 16 + m16) * PADK + quad * 8;
#pragma unroll
        for (int ks = 0; ks < 4; ks++) {
            half8 bfrag = *(const half8*)(bbase + ks * 32);
            accv[nt] = __builtin_amdgcn_mfma_f32_16x16x32_f16(afrag[ks], bfrag, accv[nt], 0, 0, 0);
        }
    }
    // ---- epilogue: D col=lane&15 (feat), row=quad*4+reg (node) ----
#pragma unroll
    for (int nt = 0; nt < 4; nt++) {
#pragma unroll
        for (int r = 0; r < 4; r++) {
            int node = nd0 + quad * 4 + r;
            float v = fmaxf(accv[nt][r] + bias[nt], 0.0f);
            hout[(size_t)node * 64 + nt * 16 + m16] = __float2half(v);
        }
    }
}

// ---------------- global mean pool (batch is sorted, h is fp16) ----------------
__global__ __launch_bounds__(256) void gnn_pool(const __half* __restrict__ h,
                                                const int* __restrict__ batch,
                                                float* __restrict__ gsum,
                                                float* __restrict__ gcnt, int n) {
    int lane = threadIdx.x & 63, wv = threadIdx.x >> 6;
    int gw = blockIdx.x * 4 + wv;
    int start = gw * 64;
    if (start >= n) return;
    int cnt_here = min(64, n - start);
    int bi = start + lane;
    if (bi >= n) bi = n - 1;
    int myb = batch[bi];
    int b_first = __shfl(myb, 0);
    int b_last = __shfl(myb, cnt_here - 1);
    if (b_first == b_last && cnt_here == 64) {
        float a0 = 0, a1 = 0, a2 = 0, a3 = 0, a4 = 0, a5 = 0, a6 = 0, a7 = 0;
        const __half* p = h + (size_t)start * 64 + lane;
#pragma unroll
        for (int i = 0; i < 64; i += 8) {
            a0 += __half2float(p[(i + 0) * 64]);
            a1 += __half2float(p[(i + 1) * 64]);
            a2 += __half2float(p[(i + 2) * 64]);
            a3 += __half2float(p[(i + 3) * 64]);
            a4 += __half2float(p[(i + 4) * 64]);
            a5 += __half2float(p[(i + 5) * 64]);
            a6 += __half2float(p[(i + 6) * 64]);
            a7 += __half2float(p[(i + 7) * 64]);
        }
        float acc = ((a0 + a1) + (a2 + a3)) + ((a4 + a5) + (a6 + a7));
        atomicAdd(&gsum[b_first * 64 + lane], acc);
        if (lane == 0) atomicAdd(&gcnt[b_first], 64.0f);
        return;
    }
    float acc = 0.0f;
    int cnt = 0;
    int cur = b_first;
    for (int i = 0; i < cnt_here; i++) {
        int g = __shfl(myb, i);
        if (g != cur) {
            atomicAdd(&gsum[cur * 64 + lane], acc);
            if (lane == 0) atomicAdd(&gcnt[cur], (float)cnt);
            acc = 0.0f;
            cnt = 0;
            cur = g;
        }
        acc += __half2float(h[(size_t)(start + i) * 64 + lane]);
        cnt++;
    }
    atomicAdd(&gsum[cur * 64 + lane], acc);
    if (lane == 0) atomicAdd(&gcnt[cur], (float)cnt);
}

// ---------------- head ----------------
__global__ __launch_bounds__(256) void gnn_head(const float* __restrict__ gsum,
                                                const float* __restrict__ gcnt,
                                                const float* __restrict__ l0W,
                                                const float* __restrict__ l0b,
                                                const float* __restrict__ outW,
                                                const float* __restrict__ outb,
                                                float* __restrict__ out, int G, int OUT) {
    __shared__ float gm[64 * 64];
    __shared__ float t2[64 * 64];
    int tid = threadIdx.x;
    for (int i = tid; i < G * 64; i += 256) {
        int r = i >> 6;
        gm[i] = gsum[i] / fmaxf(gcnt[r], 1.0f);
    }
    __syncthreads();
    for (int i = tid; i < G * 64; i += 256) {
        int r = i >> 6, c = i & 63;
        float s = l0b[c];
#pragma unroll 8
        for (int k = 0; k < 64; k++) s += gm[(r << 6) + k] * l0W[(k << 6) + c];
        t2[i] = fmaxf(s, 0.0f);
    }
    __syncthreads();
    for (int i = tid; i < G * OUT; i += 256) {
        int r = i / OUT, c = i - r * OUT;
        float s = outb[c];
#pragma unroll 8
        for (int k = 0; k < 64; k++) s += t2[(r << 6) + k] * outW[k * OUT + c];
        out[i] = s;
    }
}

extern "C" void kernel_launch(void* const* d_in, const int* in_sizes, int n_in,
                              void* d_out, int out_size, void* d_ws, size_t ws_size,
                              hipStream_t stream) {
    const float* x = (const float*)d_in[0];
    const int* ei = (const int*)d_in[1];
    const int* batch = (const int*)d_in[2];
    const float* Wl[3] = {(const float*)d_in[3], (const float*)d_in[6], (const float*)d_in[9]};
    const float* bl[3] = {(const float*)d_in[4], (const float*)d_in[7], (const float*)d_in[10]};
    const float* Wr[3] = {(const float*)d_in[5], (const float*)d_in[8], (const float*)d_in[11]};
    const float* l0W = (const float*)d_in[12];
    const float* l0b = (const float*)d_in[13];
    const float* outW = (const float*)d_in[14];
    const float* outb = (const float*)d_in[15];

    int N = in_sizes[2];
    int E = in_sizes[1] / 2;
    int OUT = 10;
    int G = out_size / OUT;
    const int* src = ei;
    const int* dst = ei + E;
    int NBKT = (N + BNODES - 1) >> BSH;

    char* ws = (char*)d_ws;
    size_t off = 0;
    auto alloc = [&](size_t b) -> char* {
        char* p = ws + off;
        off = (off + b + 255) & ~(size_t)255;
        return p;
    };
    int* row_ptr = (int*)alloc((size_t)(N + 1) * 4);
    int* csr_src = (int*)alloc((size_t)E * 4);
    float* inv_deg = (float*)alloc((size_t)N * 4);
    int* bkt_cnt = (int*)alloc((size_t)NBKT * 4);
    int* bkt_base = (int*)alloc((size_t)(NBKT + 1) * 4);
    int* bkt_cur = (int*)alloc((size_t)NBKT * 4);
    unsigned int* pairs = (unsigned int*)alloc((size_t)E * 4);
    __half* x16 = (__half*)alloc((size_t)(N + 1) * 64 * 2);  // +1 sentinel row
    __half* hA = (__half*)alloc((size_t)(N + 1) * 64 * 2);
    __half* hB = (__half*)alloc((size_t)(N + 1) * 64 * 2);
    float* gsum = (float*)alloc((size_t)G * 64 * 4);
    float* gcnt = (float*)alloc((size_t)G * 4);

    hipMemsetAsync(bkt_cnt, 0, (size_t)NBKT * 4, stream);

    int n4 = N * 64 / 4;
    int cvt_blocks = HIST_BLOCKS + (n4 + 255) / 256;
    gnn_cvt_hist<<<cvt_blocks, 256, 0, stream>>>((const float4*)x, (ushort4*)x16, n4,
                                                 dst, bkt_cnt, NBKT, E, x16, hA, hB, N);
    gnn_bkt_scan<<<1, 256, 0, stream>>>(bkt_cnt, bkt_base, bkt_cur, row_ptr, gsum, gcnt,
                                        NBKT, N, G);
    gnn_bkt_scatter<<<SC_BLOCKS, 256, 0, stream>>>(src, dst, bkt_cur, pairs, E, NBKT);
    gnn_bkt_csr<<<NBKT, 256, 0, stream>>>(pairs, bkt_base, row_ptr, inv_deg, csr_src, N);

    int ngroups = (N + 15) >> 4;
    int sage_blocks = (ngroups + WPB - 1) / WPB;
    gnn_sage<<<sage_blocks, 512, 0, stream>>>(x16, hA, row_ptr, csr_src, inv_deg,
                                              Wl[0], bl[0], Wr[0], N);
    gnn_sage<<<sage_blocks, 512, 0, stream>>>(hA, hB, row_ptr, csr_src, inv_deg,
                                              Wl[1], bl[1], Wr[1], N);
    gnn_sage<<<sage_blocks, 512, 0, stream>>>(hB, hA, row_ptr, csr_src, inv_deg,
                                              Wl[2], bl[2], Wr[2], N);

    int pool_blocks = ((N + 63) / 64 + 3) / 4;
    gnn_pool<<<pool_blocks, 256, 0, stream>>>(hA, batch, gsum, gcnt, N);
    gnn_head<<<1, 256, 0, stream>>>(gsum, gcnt, l0W, l0b, outW, outb, (float*)d_out, G, OUT);
}

// Round 14
// 383.393 us; speedup vs baseline: 2.5108x; 1.1674x over previous
//
#include <hip/hip_runtime.h>
#include <hip/hip_fp16.h>

#define WPB 8     // waves per sage block (512 threads)
#define PADK 136  // f16 elems per LDS row: 128 + 8 pad (16B-aligned rows)
#define BSH 8     // bucket shift: 256 nodes per bucket
#define BNODES 256
#define SC_BLOCKS 256
#define HIST_BLOCKS 256

typedef _Float16 half8 __attribute__((ext_vector_type(8)));
typedef float floatx4 __attribute__((ext_vector_type(4)));

#define TS16(v) (((((v)[0] + (v)[1]) + ((v)[2] + (v)[3])) + (((v)[4] + (v)[5]) + ((v)[6] + (v)[7]))) + \
                 ((((v)[8] + (v)[9]) + ((v)[10] + (v)[11])) + (((v)[12] + (v)[13]) + ((v)[14] + (v)[15]))))

// ---------------- fused: bucket histogram (blocks 0..255) + f32->f16 convert (rest) ----------------
__global__ __launch_bounds__(256) void gnn_cvt_hist(const float4* __restrict__ in,
                                                    ushort4* __restrict__ out, int n4,
                                                    const int* __restrict__ dst,
                                                    int* __restrict__ bkt_cnt, int nbkt, int E,
                                                    __half* __restrict__ x16,
                                                    __half* __restrict__ hA,
                                                    __half* __restrict__ hB, int N) {
    if (blockIdx.x < HIST_BLOCKS) {
        __shared__ int h[512];
        for (int i = threadIdx.x; i < nbkt; i += 256) h[i] = 0;
        __syncthreads();
        const int stride = HIST_BLOCKS * 256;
        for (int e = blockIdx.x * 256 + threadIdx.x; e < E; e += stride)
            atomicAdd(&h[dst[e] >> BSH], 1);
        __syncthreads();
        for (int i = threadIdx.x; i < nbkt; i += 256) {
            int v = h[i];
            if (v) atomicAdd(&bkt_cnt[i], v);
        }
        return;
    }
    int i = (blockIdx.x - HIST_BLOCKS) * 256 + threadIdx.x;
    if (i < 64) {  // zero sentinel row N of all three feature buffers
        x16[(size_t)N * 64 + i] = __ushort_as_half((unsigned short)0);
        hA[(size_t)N * 64 + i] = __ushort_as_half((unsigned short)0);
        hB[(size_t)N * 64 + i] = __ushort_as_half((unsigned short)0);
    }
    if (i < n4) {
        float4 f = in[i];
        ushort4 o;
        o.x = __half_as_ushort(__float2half(f.x));
        o.y = __half_as_ushort(__float2half(f.y));
        o.z = __half_as_ushort(__float2half(f.z));
        o.w = __half_as_ushort(__float2half(f.w));
        out[i] = o;
    }
}

// ---------------- bucket scan (1 wave) + zero gsum/gcnt (fused) ----------------
__global__ __launch_bounds__(256) void gnn_bkt_scan(const int* __restrict__ bkt_cnt,
                                                    int* __restrict__ bkt_base,
                                                    int* __restrict__ bkt_cur,
                                                    int* __restrict__ row_ptr,
                                                    float* __restrict__ gsum,
                                                    float* __restrict__ gcnt,
                                                    int nbkt, int N, int G) {
    int tid = threadIdx.x;
    for (int i = tid; i < G * 64; i += 256) gsum[i] = 0.0f;
    for (int i = tid; i < G; i += 256) gcnt[i] = 0.0f;
    if (tid < 64) {
        int lane = tid;
        int carry = 0;
        for (int base = 0; base < nbkt; base += 64) {
            int idx = base + lane;
            int v = (idx < nbkt) ? bkt_cnt[idx] : 0;
            int x = v;
#pragma unroll
            for (int off = 1; off < 64; off <<= 1) {
                int y = __shfl_up(x, off);
                if (lane >= off) x += y;
            }
            if (idx < nbkt) {
                bkt_base[idx] = carry + (x - v);
                bkt_cur[idx] = carry + (x - v);
            }
            carry += __shfl(x, 63);
        }
        if (lane == 0) {
            bkt_base[nbkt] = carry;
            row_ptr[N] = carry;
        }
    }
}

// ---------------- block-aggregated two-phase scatter (packed uint32) ----------------
__global__ __launch_bounds__(256) void gnn_bkt_scatter(const int* __restrict__ src,
                                                       const int* __restrict__ dst,
                                                       int* __restrict__ bkt_cur,
                                                       unsigned int* __restrict__ pairs,
                                                       int E, int nbkt) {
    __shared__ int hist[512];
    __shared__ int cur[512];
    int tid = threadIdx.x;
    int chunk = (E + gridDim.x - 1) / gridDim.x;
    int e0 = blockIdx.x * chunk;
    int e1 = min(E, e0 + chunk);
    for (int i = tid; i < nbkt; i += 256) hist[i] = 0;
    __syncthreads();
    for (int e = e0 + tid; e < e1; e += 256) atomicAdd(&hist[dst[e] >> BSH], 1);
    __syncthreads();
    for (int b = tid; b < nbkt; b += 256) {
        int c = hist[b];
        cur[b] = c ? atomicAdd(&bkt_cur[b], c) : 0;
    }
    __syncthreads();
    for (int e = e0 + tid; e < e1; e += 256) {
        int d = dst[e];
        int b = d >> BSH;
        int p = atomicAdd(&cur[b], 1);
        pairs[p] = (unsigned int)src[e] | ((unsigned int)(d & (BNODES - 1)) << 24);
    }
}

// ---------------- per-bucket CSR finalize ----------------
__global__ __launch_bounds__(256) void gnn_bkt_csr(const unsigned int* __restrict__ pairs,
                                                   const int* __restrict__ bkt_base,
                                                   int* __restrict__ row_ptr,
                                                   float* __restrict__ inv_deg,
                                                   int* __restrict__ csr_src, int N) {
    __shared__ int hist[BNODES];
    __shared__ int excl[BNODES];
    __shared__ int cur[BNODES];
    int b = blockIdx.x;
    int base = bkt_base[b];
    int cnt = bkt_base[b + 1] - base;
    int nd0 = b << BSH;
    int tid = threadIdx.x;
    hist[tid] = 0;
    __syncthreads();
    for (int i = tid; i < cnt; i += 256) atomicAdd(&hist[pairs[base + i] >> 24], 1);
    __syncthreads();
    if (tid < 64) {
        int carry = 0;
#pragma unroll
        for (int c = 0; c < BNODES; c += 64) {
            int v = hist[c + tid];
            int x = v;
#pragma unroll
            for (int off = 1; off < 64; off <<= 1) {
                int y = __shfl_up(x, off);
                if (tid >= off) x += y;
            }
            excl[c + tid] = carry + (x - v);
            carry += __shfl(x, 63);
        }
    }
    __syncthreads();
    {
        int node = nd0 + tid;
        if (node < N) {
            row_ptr[node] = base + excl[tid];
            int d = hist[tid];
            inv_deg[node] = 1.0f / (float)(d > 1 ? d : 1);
        }
        cur[tid] = excl[tid];
    }
    __syncthreads();
    for (int i = tid; i < cnt; i += 256) {
        unsigned int u = pairs[base + i];
        int j = u >> 24;
        int pos = atomicAdd(&cur[j], 1);
        csr_src[base + pos] = (int)(u & 0xFFFFFFu);
    }
}

// ---------------- fused SAGE layer (fp16, paired-node gather + MFMA) — R10-verbatim body ----------------
// 8 waves/block share one weight copy (52.2 KB LDS -> 3 blocks/CU); one 16-node
// group per wave; OOB lanes gather from zeroed sentinel row n (no cndmask).
// NOTE: this exact body measured 60 µs / WRITE=12.5MB (no spill). Do NOT reshape
// the gather loop — R11/R12/R13 variants all tipped the regalloc cliff (spill).
__global__ __launch_bounds__(512, 6) void gnn_sage(const __half* __restrict__ hin,
                                                   __half* __restrict__ hout,
                                                   const int* __restrict__ row_ptr,
                                                   const int* __restrict__ csr_src,
                                                   const float* __restrict__ inv_deg,
                                                   const float* __restrict__ Wl,
                                                   const float* __restrict__ bl,
                                                   const float* __restrict__ Wr, int n) {
    __shared__ _Float16 w_lds[64 * PADK];        // W2^T: [n][k], k = [Wl | Wr] (17408 B)
    __shared__ _Float16 in_lds[WPB][16 * PADK];  // per-wave [m][k] tile (4352 B each)
    int tid = threadIdx.x, lane = tid & 63, wv = tid >> 6;
    for (int i = tid; i < 64 * 64; i += 512) {
        int k = i >> 6, nn = i & 63;
        w_lds[nn * PADK + k] = (_Float16)Wl[i];
        w_lds[nn * PADK + 64 + k] = (_Float16)Wr[i];
    }
    __syncthreads();
    int ngroups = (n + 15) >> 4;
    int g = blockIdx.x * WPB + wv;
    if (g >= ngroups) return;
    int m16 = lane & 15, quad = lane >> 4;
    float bias[4];
#pragma unroll
    for (int nt = 0; nt < 4; nt++) bias[nt] = bl[nt * 16 + m16];
    _Float16* my_in = in_lds[wv];
    const _Float16* hin16 = (const _Float16*)hin;
    int nd0 = g << 4;
    // ---- gather phase: 8 node-pairs, sentinel row n for padding ----
    for (int j2 = 0; j2 < 16; j2 += 2) {
        int ndA = min(nd0 + j2, n - 1);
        int ndB = min(nd0 + j2 + 1, n - 1);
        int s0A = row_ptr[ndA], s1A = row_ptr[ndA + 1];
        int s0B = row_ptr[ndB], s1B = row_ptr[ndB + 1];
        float idgA = inv_deg[ndA], idgB = inv_deg[ndB];
        // root rows -> K = 64..127
        my_in[j2 * PADK + 64 + lane] = hin16[(size_t)ndA * 64 + lane];
        my_in[(j2 + 1) * PADK + 64 + lane] = hin16[(size_t)ndB * 64 + lane];
        float accA = 0.0f, accB = 0.0f;
        int cbA = min(64, s1A - s0A);
        int cbB = min(64, s1B - s0B);
        int eA = (lane < cbA) ? csr_src[s0A + lane] : n;  // n = zeroed sentinel row
        int eB = (lane < cbB) ? csr_src[s0B + lane] : n;
#pragma unroll
        for (int ib = 0; ib < 4; ib++) {
            const int i0 = ib * 16;
            if (i0 < cbA) {
                float vA[16];
#pragma unroll
                for (int j = 0; j < 16; j++) {
                    int sj = __shfl(eA, i0 + j);
                    vA[j] = __half2float(hin[(size_t)sj * 64 + lane]);
                }
                accA += TS16(vA);
            }
            if (i0 < cbB) {
                float vB[16];
#pragma unroll
                for (int j = 0; j < 16; j++) {
                    int sj = __shfl(eB, i0 + j);
                    vB[j] = __half2float(hin[(size_t)sj * 64 + lane]);
                }
                accB += TS16(vB);
            }
        }
        // rare tails (deg > 64)
        for (int base = s0A + 64; base < s1A; base += 64) {
            int cb = min(64, s1A - base);
            int ei = (lane < cb) ? csr_src[base + lane] : n;
#pragma unroll
            for (int ib = 0; ib < 4; ib++) {
                const int i0 = ib * 16;
                if (i0 < cb) {
                    float v[16];
#pragma unroll
                    for (int j = 0; j < 16; j++) {
                        int s = __shfl(ei, i0 + j);
                        v[j] = __half2float(hin[(size_t)s * 64 + lane]);
                    }
                    accA += TS16(v);
                }
            }
        }
        for (int base = s0B + 64; base < s1B; base += 64) {
            int cb = min(64, s1B - base);
            int ei = (lane < cb) ? csr_src[base + lane] : n;
#pragma unroll
            for (int ib = 0; ib < 4; ib++) {
                const int i0 = ib * 16;
                if (i0 < cb) {
                    float v[16];
#pragma unroll
                    for (int j = 0; j < 16; j++) {
                        int s = __shfl(ei, i0 + j);
                        v[j] = __half2float(hin[(size_t)s * 64 + lane]);
                    }
                    accB += TS16(v);
                }
            }
        }
        my_in[j2 * PADK + lane] = (_Float16)(accA * idgA);
        my_in[(j2 + 1) * PADK + lane] = (_Float16)(accB * idgB);
    }
    // ---- MFMA phase: D[16 nodes][64 feats] = A[16][128] * B[128][64] ----
    half8 afrag[4];
    const _Float16* abase = my_in + m16 * PADK + quad * 8;
#pragma unroll
    for (int ks = 0; ks < 4; ks++) afrag[ks] = *(const half8*)(abase + ks * 32);
    floatx4 accv[4];
#pragma unroll
    for (int nt = 0; nt < 4; nt++) {
        accv[nt].x = 0.f; accv[nt].y = 0.f; accv[nt].z = 0.f; accv[nt].w = 0.f;
    }
#pragma unroll
    for (int nt = 0; nt < 4; nt++) {
        const _Float16* bbase = w_lds + (nt * 16 + m16) * PADK + quad * 8;
#pragma unroll
        for (int ks = 0; ks < 4; ks++) {
            half8 bfrag = *(const half8*)(bbase + ks * 32);
            accv[nt] = __builtin_amdgcn_mfma_f32_16x16x32_f16(afrag[ks], bfrag, accv[nt], 0, 0, 0);
        }
    }
    // ---- epilogue: D col=lane&15 (feat), row=quad*4+reg (node) ----
#pragma unroll
    for (int nt = 0; nt < 4; nt++) {
#pragma unroll
        for (int r = 0; r < 4; r++) {
            int node = nd0 + quad * 4 + r;
            if (node < n) {
                float v = fmaxf(accv[nt][r] + bias[nt], 0.0f);
                hout[(size_t)node * 64 + nt * 16 + m16] = __float2half(v);
            }
        }
    }
}

// ---------------- global mean pool (batch is sorted, h is fp16) ----------------
__global__ __launch_bounds__(256) void gnn_pool(const __half* __restrict__ h,
                                                const int* __restrict__ batch,
                                                float* __restrict__ gsum,
                                                float* __restrict__ gcnt, int n) {
    int lane = threadIdx.x & 63, wv = threadIdx.x >> 6;
    int gw = blockIdx.x * 4 + wv;
    int start = gw * 64;
    if (start >= n) return;
    int cnt_here = min(64, n - start);
    int bi = start + lane;
    if (bi >= n) bi = n - 1;
    int myb = batch[bi];
    int b_first = __shfl(myb, 0);
    int b_last = __shfl(myb, cnt_here - 1);
    if (b_first == b_last && cnt_here == 64) {
        float a0 = 0, a1 = 0, a2 = 0, a3 = 0, a4 = 0, a5 = 0, a6 = 0, a7 = 0;
        const __half* p = h + (size_t)start * 64 + lane;
#pragma unroll
        for (int i = 0; i < 64; i += 8) {
            a0 += __half2float(p[(i + 0) * 64]);
            a1 += __half2float(p[(i + 1) * 64]);
            a2 += __half2float(p[(i + 2) * 64]);
            a3 += __half2float(p[(i + 3) * 64]);
            a4 += __half2float(p[(i + 4) * 64]);
            a5 += __half2float(p[(i + 5) * 64]);
            a6 += __half2float(p[(i + 6) * 64]);
            a7 += __half2float(p[(i + 7) * 64]);
        }
        float acc = ((a0 + a1) + (a2 + a3)) + ((a4 + a5) + (a6 + a7));
        atomicAdd(&gsum[b_first * 64 + lane], acc);
        if (lane == 0) atomicAdd(&gcnt[b_first], 64.0f);
        return;
    }
    float acc = 0.0f;
    int cnt = 0;
    int cur = b_first;
    for (int i = 0; i < cnt_here; i++) {
        int g = __shfl(myb, i);
        if (g != cur) {
            atomicAdd(&gsum[cur * 64 + lane], acc);
            if (lane == 0) atomicAdd(&gcnt[cur], (float)cnt);
            acc = 0.0f;
            cnt = 0;
            cur = g;
        }
        acc += __half2float(h[(size_t)(start + i) * 64 + lane]);
        cnt++;
    }
    atomicAdd(&gsum[cur * 64 + lane], acc);
    if (lane == 0) atomicAdd(&gcnt[cur], (float)cnt);
}

// ---------------- head ----------------
__global__ __launch_bounds__(256) void gnn_head(const float* __restrict__ gsum,
                                                const float* __restrict__ gcnt,
                                                const float* __restrict__ l0W,
                                                const float* __restrict__ l0b,
                                                const float* __restrict__ outW,
                                                const float* __restrict__ outb,
                                                float* __restrict__ out, int G, int OUT) {
    __shared__ float gm[64 * 64];
    __shared__ float t2[64 * 64];
    int tid = threadIdx.x;
    for (int i = tid; i < G * 64; i += 256) {
        int r = i >> 6;
        gm[i] = gsum[i] / fmaxf(gcnt[r], 1.0f);
    }
    __syncthreads();
    for (int i = tid; i < G * 64; i += 256) {
        int r = i >> 6, c = i & 63;
        float s = l0b[c];
#pragma unroll 8
        for (int k = 0; k < 64; k++) s += gm[(r << 6) + k] * l0W[(k << 6) + c];
        t2[i] = fmaxf(s, 0.0f);
    }
    __syncthreads();
    for (int i = tid; i < G * OUT; i += 256) {
        int r = i / OUT, c = i - r * OUT;
        float s = outb[c];
#pragma unroll 8
        for (int k = 0; k < 64; k++) s += t2[(r << 6) + k] * outW[k * OUT + c];
        out[i] = s;
    }
}

extern "C" void kernel_launch(void* const* d_in, const int* in_sizes, int n_in,
                              void* d_out, int out_size, void* d_ws, size_t ws_size,
                              hipStream_t stream) {
    const float* x = (const float*)d_in[0];
    const int* ei = (const int*)d_in[1];
    const int* batch = (const int*)d_in[2];
    const float* Wl[3] = {(const float*)d_in[3], (const float*)d_in[6], (const float*)d_in[9]};
    const float* bl[3] = {(const float*)d_in[4], (const float*)d_in[7], (const float*)d_in[10]};
    const float* Wr[3] = {(const float*)d_in[5], (const float*)d_in[8], (const float*)d_in[11]};
    const float* l0W = (const float*)d_in[12];
    const float* l0b = (const float*)d_in[13];
    const float* outW = (const float*)d_in[14];
    const float* outb = (const float*)d_in[15];

    int N = in_sizes[2];
    int E = in_sizes[1] / 2;
    int OUT = 10;
    int G = out_size / OUT;
    const int* src = ei;
    const int* dst = ei + E;
    int NBKT = (N + BNODES - 1) >> BSH;

    char* ws = (char*)d_ws;
    size_t off = 0;
    auto alloc = [&](size_t b) -> char* {
        char* p = ws + off;
        off = (off + b + 255) & ~(size_t)255;
        return p;
    };
    int* row_ptr = (int*)alloc((size_t)(N + 1) * 4);
    int* csr_src = (int*)alloc((size_t)E * 4);
    float* inv_deg = (float*)alloc((size_t)N * 4);
    int* bkt_cnt = (int*)alloc((size_t)NBKT * 4);
    int* bkt_base = (int*)alloc((size_t)(NBKT + 1) * 4);
    int* bkt_cur = (int*)alloc((size_t)NBKT * 4);
    unsigned int* pairs = (unsigned int*)alloc((size_t)E * 4);
    __half* x16 = (__half*)alloc((size_t)(N + 1) * 64 * 2);  // +1 sentinel row
    __half* hA = (__half*)alloc((size_t)(N + 1) * 64 * 2);
    __half* hB = (__half*)alloc((size_t)(N + 1) * 64 * 2);
    float* gsum = (float*)alloc((size_t)G * 64 * 4);
    float* gcnt = (float*)alloc((size_t)G * 4);

    hipMemsetAsync(bkt_cnt, 0, (size_t)NBKT * 4, stream);

    int n4 = N * 64 / 4;
    int cvt_blocks = HIST_BLOCKS + (n4 + 255) / 256;
    gnn_cvt_hist<<<cvt_blocks, 256, 0, stream>>>((const float4*)x, (ushort4*)x16, n4,
                                                 dst, bkt_cnt, NBKT, E, x16, hA, hB, N);
    gnn_bkt_scan<<<1, 256, 0, stream>>>(bkt_cnt, bkt_base, bkt_cur, row_ptr, gsum, gcnt,
                                        NBKT, N, G);
    gnn_bkt_scatter<<<SC_BLOCKS, 256, 0, stream>>>(src, dst, bkt_cur, pairs, E, NBKT);
    gnn_bkt_csr<<<NBKT, 256, 0, stream>>>(pairs, bkt_base, row_ptr, inv_deg, csr_src, N);

    int ngroups = (N + 15) >> 4;
    int sage_blocks = (ngroups + WPB - 1) / WPB;
    gnn_sage<<<sage_blocks, 512, 0, stream>>>(x16, hA, row_ptr, csr_src, inv_deg,
                                              Wl[0], bl[0], Wr[0], N);
    gnn_sage<<<sage_blocks, 512, 0, stream>>>(hA, hB, row_ptr, csr_src, inv_deg,
                                              Wl[1], bl[1], Wr[1], N);
    gnn_sage<<<sage_blocks, 512, 0, stream>>>(hB, hA, row_ptr, csr_src, inv_deg,
                                              Wl[2], bl[2], Wr[2], N);

    int pool_blocks = ((N + 63) / 64 + 3) / 4;
    gnn_pool<<<pool_blocks, 256, 0, stream>>>(hA, batch, gsum, gcnt, N);
    gnn_head<<<1, 256, 0, stream>>>(gsum, gcnt, l0W, l0b, outW, outb, (float*)d_out, G, OUT);
}

// Round 15
// 374.668 us; speedup vs baseline: 2.5692x; 1.0233x over previous
//
#include <hip/hip_runtime.h>
#include <hip/hip_fp16.h>

#define WPB 8     // waves per sage block (512 threads)
#define PADK 136  // f16 elems per LDS row: 128 + 8 pad (16B-aligned rows)
#define BSH 8     // bucket shift: 256 nodes per bucket
#define BNODES 256
#define SC_BLOCKS 256
#define PRE_BLOCKS 256

typedef _Float16 half8 __attribute__((ext_vector_type(8)));
typedef float floatx4 __attribute__((ext_vector_type(4)));

#define TS16(v) (((((v)[0] + (v)[1]) + ((v)[2] + (v)[3])) + (((v)[4] + (v)[5]) + ((v)[6] + (v)[7]))) + \
                 ((((v)[8] + (v)[9]) + ((v)[10] + (v)[11])) + (((v)[12] + (v)[13]) + ((v)[14] + (v)[15]))))

// ---------------- pre: bucket hist (dst) + graph hist (batch) + sentinel zeroing ----------------
__global__ __launch_bounds__(256) void gnn_pre(const int* __restrict__ dst,
                                               int* __restrict__ bkt_cnt, int nbkt, int E,
                                               const int* __restrict__ batch,
                                               float* __restrict__ gcnt, int N,
                                               __half* __restrict__ hA, __half* __restrict__ hB) {
    __shared__ int h[512];
    __shared__ int gb[64];
    int tid = threadIdx.x;
    for (int i = tid; i < nbkt; i += 256) h[i] = 0;
    if (tid < 64) gb[tid] = 0;
    __syncthreads();
    const int stride = PRE_BLOCKS * 256;
    for (int e = blockIdx.x * 256 + tid; e < E; e += stride)
        atomicAdd(&h[dst[e] >> BSH], 1);
    for (int i = blockIdx.x * 256 + tid; i < N; i += stride)
        atomicAdd(&gb[batch[i]], 1);
    __syncthreads();
    for (int i = tid; i < nbkt; i += 256) {
        int v = h[i];
        if (v) atomicAdd(&bkt_cnt[i], v);
    }
    if (tid < 64) {
        int v = gb[tid];
        if (v) atomicAdd(&gcnt[tid], (float)v);
    }
    if (blockIdx.x == 0 && tid < 64) {  // zero sentinel row N of hA, hB
        hA[(size_t)N * 64 + tid] = __ushort_as_half((unsigned short)0);
        hB[(size_t)N * 64 + tid] = __ushort_as_half((unsigned short)0);
    }
}

// ---------------- bucket scan (1 wave) ----------------
__global__ void gnn_bkt_scan(const int* __restrict__ bkt_cnt, int* __restrict__ bkt_base,
                             int* __restrict__ bkt_cur, int* __restrict__ row_ptr,
                             int nbkt, int N) {
    int lane = threadIdx.x;
    int carry = 0;
    for (int base = 0; base < nbkt; base += 64) {
        int idx = base + lane;
        int v = (idx < nbkt) ? bkt_cnt[idx] : 0;
        int x = v;
#pragma unroll
        for (int off = 1; off < 64; off <<= 1) {
            int y = __shfl_up(x, off);
            if (lane >= off) x += y;
        }
        if (idx < nbkt) {
            bkt_base[idx] = carry + (x - v);
            bkt_cur[idx] = carry + (x - v);
        }
        carry += __shfl(x, 63);
    }
    if (lane == 0) {
        bkt_base[nbkt] = carry;
        row_ptr[N] = carry;
    }
}

// ---------------- block-aggregated two-phase scatter (packed uint32) ----------------
__global__ __launch_bounds__(256) void gnn_bkt_scatter(const int* __restrict__ src,
                                                       const int* __restrict__ dst,
                                                       int* __restrict__ bkt_cur,
                                                       unsigned int* __restrict__ pairs,
                                                       int E, int nbkt) {
    __shared__ int hist[512];
    __shared__ int cur[512];
    int tid = threadIdx.x;
    int chunk = (E + gridDim.x - 1) / gridDim.x;
    int e0 = blockIdx.x * chunk;
    int e1 = min(E, e0 + chunk);
    for (int i = tid; i < nbkt; i += 256) hist[i] = 0;
    __syncthreads();
    for (int e = e0 + tid; e < e1; e += 256) atomicAdd(&hist[dst[e] >> BSH], 1);
    __syncthreads();
    for (int b = tid; b < nbkt; b += 256) {
        int c = hist[b];
        cur[b] = c ? atomicAdd(&bkt_cur[b], c) : 0;
    }
    __syncthreads();
    for (int e = e0 + tid; e < e1; e += 256) {
        int d = dst[e];
        int b = d >> BSH;
        int p = atomicAdd(&cur[b], 1);
        pairs[p] = (unsigned int)src[e] | ((unsigned int)(d & (BNODES - 1)) << 24);
    }
}

// ---------------- per-bucket CSR finalize ----------------
__global__ __launch_bounds__(256) void gnn_bkt_csr(const unsigned int* __restrict__ pairs,
                                                   const int* __restrict__ bkt_base,
                                                   int* __restrict__ row_ptr,
                                                   float* __restrict__ inv_deg,
                                                   int* __restrict__ csr_src, int N) {
    __shared__ int hist[BNODES];
    __shared__ int excl[BNODES];
    __shared__ int cur[BNODES];
    int b = blockIdx.x;
    int base = bkt_base[b];
    int cnt = bkt_base[b + 1] - base;
    int nd0 = b << BSH;
    int tid = threadIdx.x;
    hist[tid] = 0;
    __syncthreads();
    for (int i = tid; i < cnt; i += 256) atomicAdd(&hist[pairs[base + i] >> 24], 1);
    __syncthreads();
    if (tid < 64) {
        int carry = 0;
#pragma unroll
        for (int c = 0; c < BNODES; c += 64) {
            int v = hist[c + tid];
            int x = v;
#pragma unroll
            for (int off = 1; off < 64; off <<= 1) {
                int y = __shfl_up(x, off);
                if (tid >= off) x += y;
            }
            excl[c + tid] = carry + (x - v);
            carry += __shfl(x, 63);
        }
    }
    __syncthreads();
    {
        int node = nd0 + tid;
        if (node < N) {
            row_ptr[node] = base + excl[tid];
            int d = hist[tid];
            inv_deg[node] = 1.0f / (float)(d > 1 ? d : 1);
        }
        cur[tid] = excl[tid];
    }
    __syncthreads();
    for (int i = tid; i < cnt; i += 256) {
        unsigned int u = pairs[base + i];
        int j = u >> 24;
        int pos = atomicAdd(&cur[j], 1);
        csr_src[base + pos] = (int)(u & 0xFFFFFFu);
    }
}

// ---------------- SAGE layer 1: f32 input (no cvt pass), predicated gather + MFMA ----------------
__global__ __launch_bounds__(512, 6) void gnn_sage_x(const float* __restrict__ xin,
                                                     __half* __restrict__ hout,
                                                     const int* __restrict__ row_ptr,
                                                     const int* __restrict__ csr_src,
                                                     const float* __restrict__ inv_deg,
                                                     const float* __restrict__ Wl,
                                                     const float* __restrict__ bl,
                                                     const float* __restrict__ Wr, int n) {
    __shared__ _Float16 w_lds[64 * PADK];
    __shared__ _Float16 in_lds[WPB][16 * PADK];
    int tid = threadIdx.x, lane = tid & 63, wv = tid >> 6;
    for (int i = tid; i < 64 * 64; i += 512) {
        int k = i >> 6, nn = i & 63;
        w_lds[nn * PADK + k] = (_Float16)Wl[i];
        w_lds[nn * PADK + 64 + k] = (_Float16)Wr[i];
    }
    __syncthreads();
    int ngroups = (n + 15) >> 4;
    int g = blockIdx.x * WPB + wv;
    if (g >= ngroups) return;
    int m16 = lane & 15, quad = lane >> 4;
    float bias[4];
#pragma unroll
    for (int nt = 0; nt < 4; nt++) bias[nt] = bl[nt * 16 + m16];
    _Float16* my_in = in_lds[wv];
    int nd0 = g << 4;
    for (int j2 = 0; j2 < 16; j2 += 2) {
        int ndA = min(nd0 + j2, n - 1);
        int ndB = min(nd0 + j2 + 1, n - 1);
        int s0A = row_ptr[ndA], s1A = row_ptr[ndA + 1];
        int s0B = row_ptr[ndB], s1B = row_ptr[ndB + 1];
        float idgA = inv_deg[ndA], idgB = inv_deg[ndB];
        my_in[j2 * PADK + 64 + lane] = (_Float16)xin[(size_t)ndA * 64 + lane];
        my_in[(j2 + 1) * PADK + 64 + lane] = (_Float16)xin[(size_t)ndB * 64 + lane];
        float accA = 0.0f, accB = 0.0f;
        int cbA = min(64, s1A - s0A);
        int cbB = min(64, s1B - s0B);
        int eA = (lane < cbA) ? csr_src[s0A + lane] : ndA;  // valid row; predicate per elem
        int eB = (lane < cbB) ? csr_src[s0B + lane] : ndB;
#pragma unroll
        for (int ib = 0; ib < 4; ib++) {
            const int i0 = ib * 16;
            if (i0 < cbA) {
                float vA[16];
#pragma unroll
                for (int j = 0; j < 16; j++) {
                    int sj = __shfl(eA, i0 + j);
                    float hv = xin[(size_t)sj * 64 + lane];
                    vA[j] = (i0 + j < cbA) ? hv : 0.0f;
                }
                accA += TS16(vA);
            }
            if (i0 < cbB) {
                float vB[16];
#pragma unroll
                for (int j = 0; j < 16; j++) {
                    int sj = __shfl(eB, i0 + j);
                    float hv = xin[(size_t)sj * 64 + lane];
                    vB[j] = (i0 + j < cbB) ? hv : 0.0f;
                }
                accB += TS16(vB);
            }
        }
        for (int base = s0A + 64; base < s1A; base += 64) {
            int cb = min(64, s1A - base);
            int ei = (lane < cb) ? csr_src[base + lane] : ndA;
#pragma unroll
            for (int ib = 0; ib < 4; ib++) {
                const int i0 = ib * 16;
                if (i0 < cb) {
                    float v[16];
#pragma unroll
                    for (int j = 0; j < 16; j++) {
                        int s = __shfl(ei, i0 + j);
                        float hv = xin[(size_t)s * 64 + lane];
                        v[j] = (i0 + j < cb) ? hv : 0.0f;
                    }
                    accA += TS16(v);
                }
            }
        }
        for (int base = s0B + 64; base < s1B; base += 64) {
            int cb = min(64, s1B - base);
            int ei = (lane < cb) ? csr_src[base + lane] : ndB;
#pragma unroll
            for (int ib = 0; ib < 4; ib++) {
                const int i0 = ib * 16;
                if (i0 < cb) {
                    float v[16];
#pragma unroll
                    for (int j = 0; j < 16; j++) {
                        int s = __shfl(ei, i0 + j);
                        float hv = xin[(size_t)s * 64 + lane];
                        v[j] = (i0 + j < cb) ? hv : 0.0f;
                    }
                    accB += TS16(v);
                }
            }
        }
        my_in[j2 * PADK + lane] = (_Float16)(accA * idgA);
        my_in[(j2 + 1) * PADK + lane] = (_Float16)(accB * idgB);
    }
    half8 afrag[4];
    const _Float16* abase = my_in + m16 * PADK + quad * 8;
#pragma unroll
    for (int ks = 0; ks < 4; ks++) afrag[ks] = *(const half8*)(abase + ks * 32);
    floatx4 accv[4];
#pragma unroll
    for (int nt = 0; nt < 4; nt++) {
        accv[nt].x = 0.f; accv[nt].y = 0.f; accv[nt].z = 0.f; accv[nt].w = 0.f;
    }
#pragma unroll
    for (int nt = 0; nt < 4; nt++) {
        const _Float16* bbase = w_lds + (nt * 16 + m16) * PADK + quad * 8;
#pragma unroll
        for (int ks = 0; ks < 4; ks++) {
            half8 bfrag = *(const half8*)(bbase + ks * 32);
            accv[nt] = __builtin_amdgcn_mfma_f32_16x16x32_f16(afrag[ks], bfrag, accv[nt], 0, 0, 0);
        }
    }
#pragma unroll
    for (int nt = 0; nt < 4; nt++) {
#pragma unroll
        for (int r = 0; r < 4; r++) {
            int node = nd0 + quad * 4 + r;
            if (node < n) {
                float v = fmaxf(accv[nt][r] + bias[nt], 0.0f);
                hout[(size_t)node * 64 + nt * 16 + m16] = __float2half(v);
            }
        }
    }
}

// ---------------- SAGE layer 2 (R10/R14-verbatim body — do NOT reshape gather) ----------------
__global__ __launch_bounds__(512, 6) void gnn_sage(const __half* __restrict__ hin,
                                                   __half* __restrict__ hout,
                                                   const int* __restrict__ row_ptr,
                                                   const int* __restrict__ csr_src,
                                                   const float* __restrict__ inv_deg,
                                                   const float* __restrict__ Wl,
                                                   const float* __restrict__ bl,
                                                   const float* __restrict__ Wr, int n) {
    __shared__ _Float16 w_lds[64 * PADK];
    __shared__ _Float16 in_lds[WPB][16 * PADK];
    int tid = threadIdx.x, lane = tid & 63, wv = tid >> 6;
    for (int i = tid; i < 64 * 64; i += 512) {
        int k = i >> 6, nn = i & 63;
        w_lds[nn * PADK + k] = (_Float16)Wl[i];
        w_lds[nn * PADK + 64 + k] = (_Float16)Wr[i];
    }
    __syncthreads();
    int ngroups = (n + 15) >> 4;
    int g = blockIdx.x * WPB + wv;
    if (g >= ngroups) return;
    int m16 = lane & 15, quad = lane >> 4;
    float bias[4];
#pragma unroll
    for (int nt = 0; nt < 4; nt++) bias[nt] = bl[nt * 16 + m16];
    _Float16* my_in = in_lds[wv];
    const _Float16* hin16 = (const _Float16*)hin;
    int nd0 = g << 4;
    for (int j2 = 0; j2 < 16; j2 += 2) {
        int ndA = min(nd0 + j2, n - 1);
        int ndB = min(nd0 + j2 + 1, n - 1);
        int s0A = row_ptr[ndA], s1A = row_ptr[ndA + 1];
        int s0B = row_ptr[ndB], s1B = row_ptr[ndB + 1];
        float idgA = inv_deg[ndA], idgB = inv_deg[ndB];
        my_in[j2 * PADK + 64 + lane] = hin16[(size_t)ndA * 64 + lane];
        my_in[(j2 + 1) * PADK + 64 + lane] = hin16[(size_t)ndB * 64 + lane];
        float accA = 0.0f, accB = 0.0f;
        int cbA = min(64, s1A - s0A);
        int cbB = min(64, s1B - s0B);
        int eA = (lane < cbA) ? csr_src[s0A + lane] : n;
        int eB = (lane < cbB) ? csr_src[s0B + lane] : n;
#pragma unroll
        for (int ib = 0; ib < 4; ib++) {
            const int i0 = ib * 16;
            if (i0 < cbA) {
                float vA[16];
#pragma unroll
                for (int j = 0; j < 16; j++) {
                    int sj = __shfl(eA, i0 + j);
                    vA[j] = __half2float(hin[(size_t)sj * 64 + lane]);
                }
                accA += TS16(vA);
            }
            if (i0 < cbB) {
                float vB[16];
#pragma unroll
                for (int j = 0; j < 16; j++) {
                    int sj = __shfl(eB, i0 + j);
                    vB[j] = __half2float(hin[(size_t)sj * 64 + lane]);
                }
                accB += TS16(vB);
            }
        }
        for (int base = s0A + 64; base < s1A; base += 64) {
            int cb = min(64, s1A - base);
            int ei = (lane < cb) ? csr_src[base + lane] : n;
#pragma unroll
            for (int ib = 0; ib < 4; ib++) {
                const int i0 = ib * 16;
                if (i0 < cb) {
                    float v[16];
#pragma unroll
                    for (int j = 0; j < 16; j++) {
                        int s = __shfl(ei, i0 + j);
                        v[j] = __half2float(hin[(size_t)s * 64 + lane]);
                    }
                    accA += TS16(v);
                }
            }
        }
        for (int base = s0B + 64; base < s1B; base += 64) {
            int cb = min(64, s1B - base);
            int ei = (lane < cb) ? csr_src[base + lane] : n;
#pragma unroll
            for (int ib = 0; ib < 4; ib++) {
                const int i0 = ib * 16;
                if (i0 < cb) {
                    float v[16];
#pragma unroll
                    for (int j = 0; j < 16; j++) {
                        int s = __shfl(ei, i0 + j);
                        v[j] = __half2float(hin[(size_t)s * 64 + lane]);
                    }
                    accB += TS16(v);
                }
            }
        }
        my_in[j2 * PADK + lane] = (_Float16)(accA * idgA);
        my_in[(j2 + 1) * PADK + lane] = (_Float16)(accB * idgB);
    }
    half8 afrag[4];
    const _Float16* abase = my_in + m16 * PADK + quad * 8;
#pragma unroll
    for (int ks = 0; ks < 4; ks++) afrag[ks] = *(const half8*)(abase + ks * 32);
    floatx4 accv[4];
#pragma unroll
    for (int nt = 0; nt < 4; nt++) {
        accv[nt].x = 0.f; accv[nt].y = 0.f; accv[nt].z = 0.f; accv[nt].w = 0.f;
    }
#pragma unroll
    for (int nt = 0; nt < 4; nt++) {
        const _Float16* bbase = w_lds + (nt * 16 + m16) * PADK + quad * 8;
#pragma unroll
        for (int ks = 0; ks < 4; ks++) {
            half8 bfrag = *(const half8*)(bbase + ks * 32);
            accv[nt] = __builtin_amdgcn_mfma_f32_16x16x32_f16(afrag[ks], bfrag, accv[nt], 0, 0, 0);
        }
    }
#pragma unroll
    for (int nt = 0; nt < 4; nt++) {
#pragma unroll
        for (int r = 0; r < 4; r++) {
            int node = nd0 + quad * 4 + r;
            if (node < n) {
                float v = fmaxf(accv[nt][r] + bias[nt], 0.0f);
                hout[(size_t)node * 64 + nt * 16 + m16] = __float2half(v);
            }
        }
    }
}

// ---------------- SAGE layer 3 + fused global-mean-pool epilogue ----------------
__global__ __launch_bounds__(512, 6) void gnn_sage_pool(const __half* __restrict__ hin,
                                                        const int* __restrict__ row_ptr,
                                                        const int* __restrict__ csr_src,
                                                        const float* __restrict__ inv_deg,
                                                        const float* __restrict__ Wl,
                                                        const float* __restrict__ bl,
                                                        const float* __restrict__ Wr,
                                                        const int* __restrict__ batch,
                                                        float* __restrict__ gsum, int n) {
    __shared__ _Float16 w_lds[64 * PADK];
    __shared__ _Float16 in_lds[WPB][16 * PADK];
    int tid = threadIdx.x, lane = tid & 63, wv = tid >> 6;
    for (int i = tid; i < 64 * 64; i += 512) {
        int k = i >> 6, nn = i & 63;
        w_lds[nn * PADK + k] = (_Float16)Wl[i];
        w_lds[nn * PADK + 64 + k] = (_Float16)Wr[i];
    }
    __syncthreads();
    int ngroups = (n + 15) >> 4;
    int g = blockIdx.x * WPB + wv;
    if (g >= ngroups) return;
    int m16 = lane & 15, quad = lane >> 4;
    float bias[4];
#pragma unroll
    for (int nt = 0; nt < 4; nt++) bias[nt] = bl[nt * 16 + m16];
    _Float16* my_in = in_lds[wv];
    const _Float16* hin16 = (const _Float16*)hin;
    int nd0 = g << 4;
    for (int j2 = 0; j2 < 16; j2 += 2) {
        int ndA = min(nd0 + j2, n - 1);
        int ndB = min(nd0 + j2 + 1, n - 1);
        int s0A = row_ptr[ndA], s1A = row_ptr[ndA + 1];
        int s0B = row_ptr[ndB], s1B = row_ptr[ndB + 1];
        float idgA = inv_deg[ndA], idgB = inv_deg[ndB];
        my_in[j2 * PADK + 64 + lane] = hin16[(size_t)ndA * 64 + lane];
        my_in[(j2 + 1) * PADK + 64 + lane] = hin16[(size_t)ndB * 64 + lane];
        float accA = 0.0f, accB = 0.0f;
        int cbA = min(64, s1A - s0A);
        int cbB = min(64, s1B - s0B);
        int eA = (lane < cbA) ? csr_src[s0A + lane] : n;
        int eB = (lane < cbB) ? csr_src[s0B + lane] : n;
#pragma unroll
        for (int ib = 0; ib < 4; ib++) {
            const int i0 = ib * 16;
            if (i0 < cbA) {
                float vA[16];
#pragma unroll
                for (int j = 0; j < 16; j++) {
                    int sj = __shfl(eA, i0 + j);
                    vA[j] = __half2float(hin[(size_t)sj * 64 + lane]);
                }
                accA += TS16(vA);
            }
            if (i0 < cbB) {
                float vB[16];
#pragma unroll
                for (int j = 0; j < 16; j++) {
                    int sj = __shfl(eB, i0 + j);
                    vB[j] = __half2float(hin[(size_t)sj * 64 + lane]);
                }
                accB += TS16(vB);
            }
        }
        for (int base = s0A + 64; base < s1A; base += 64) {
            int cb = min(64, s1A - base);
            int ei = (lane < cb) ? csr_src[base + lane] : n;
#pragma unroll
            for (int ib = 0; ib < 4; ib++) {
                const int i0 = ib * 16;
                if (i0 < cb) {
                    float v[16];
#pragma unroll
                    for (int j = 0; j < 16; j++) {
                        int s = __shfl(ei, i0 + j);
                        v[j] = __half2float(hin[(size_t)s * 64 + lane]);
                    }
                    accA += TS16(v);
                }
            }
        }
        for (int base = s0B + 64; base < s1B; base += 64) {
            int cb = min(64, s1B - base);
            int ei = (lane < cb) ? csr_src[base + lane] : n;
#pragma unroll
            for (int ib = 0; ib < 4; ib++) {
                const int i0 = ib * 16;
                if (i0 < cb) {
                    float v[16];
#pragma unroll
                    for (int j = 0; j < 16; j++) {
                        int s = __shfl(ei, i0 + j);
                        v[j] = __half2float(hin[(size_t)s * 64 + lane]);
                    }
                    accB += TS16(v);
                }
            }
        }
        my_in[j2 * PADK + lane] = (_Float16)(accA * idgA);
        my_in[(j2 + 1) * PADK + lane] = (_Float16)(accB * idgB);
    }
    half8 afrag[4];
    const _Float16* abase = my_in + m16 * PADK + quad * 8;
#pragma unroll
    for (int ks = 0; ks < 4; ks++) afrag[ks] = *(const half8*)(abase + ks * 32);
    floatx4 accv[4];
#pragma unroll
    for (int nt = 0; nt < 4; nt++) {
        accv[nt].x = 0.f; accv[nt].y = 0.f; accv[nt].z = 0.f; accv[nt].w = 0.f;
    }
#pragma unroll
    for (int nt = 0; nt < 4; nt++) {
        const _Float16* bbase = w_lds + (nt * 16 + m16) * PADK + quad * 8;
#pragma unroll
        for (int ks = 0; ks < 4; ks++) {
            half8 bfrag = *(const half8*)(bbase + ks * 32);
            accv[nt] = __builtin_amdgcn_mfma_f32_16x16x32_f16(afrag[ks], bfrag, accv[nt], 0, 0, 0);
        }
    }
    // ---- fused pool epilogue: relu(out)+bias summed into gsum[graph][feat] ----
    int bFirst = batch[nd0];
    int bLast = batch[min(nd0 + 15, n - 1)];
    if (bFirst == bLast && nd0 + 15 < n) {
        // fast path: all 16 nodes in one graph; reduce over r then quads
#pragma unroll
        for (int nt = 0; nt < 4; nt++) {
            float s = fmaxf(accv[nt][0] + bias[nt], 0.0f) + fmaxf(accv[nt][1] + bias[nt], 0.0f) +
                      fmaxf(accv[nt][2] + bias[nt], 0.0f) + fmaxf(accv[nt][3] + bias[nt], 0.0f);
            s += __shfl_xor(s, 16);
            s += __shfl_xor(s, 32);
            if (quad == 0) atomicAdd(&gsum[bFirst * 64 + nt * 16 + m16], s);
        }
    } else {
        // slow path (graph boundary inside group): per-node atomics
#pragma unroll
        for (int nt = 0; nt < 4; nt++) {
#pragma unroll
            for (int r = 0; r < 4; r++) {
                int node = nd0 + quad * 4 + r;
                if (node < n) {
                    int bg = batch[node];
                    float v = fmaxf(accv[nt][r] + bias[nt], 0.0f);
                    atomicAdd(&gsum[bg * 64 + nt * 16 + m16], v);
                }
            }
        }
    }
}

// ---------------- head ----------------
__global__ __launch_bounds__(256) void gnn_head(const float* __restrict__ gsum,
                                                const float* __restrict__ gcnt,
                                                const float* __restrict__ l0W,
                                                const float* __restrict__ l0b,
                                                const float* __restrict__ outW,
                                                const float* __restrict__ outb,
                                                float* __restrict__ out, int G, int OUT) {
    __shared__ float gm[64 * 64];
    __shared__ float t2[64 * 64];
    int tid = threadIdx.x;
    for (int i = tid; i < G * 64; i += 256) {
        int r = i >> 6;
        gm[i] = gsum[i] / fmaxf(gcnt[r], 1.0f);
    }
    __syncthreads();
    for (int i = tid; i < G * 64; i += 256) {
        int r = i >> 6, c = i & 63;
        float s = l0b[c];
#pragma unroll 8
        for (int k = 0; k < 64; k++) s += gm[(r << 6) + k] * l0W[(k << 6) + c];
        t2[i] = fmaxf(s, 0.0f);
    }
    __syncthreads();
    for (int i = tid; i < G * OUT; i += 256) {
        int r = i / OUT, c = i - r * OUT;
        float s = outb[c];
#pragma unroll 8
        for (int k = 0; k < 64; k++) s += t2[(r << 6) + k] * outW[k * OUT + c];
        out[i] = s;
    }
}

extern "C" void kernel_launch(void* const* d_in, const int* in_sizes, int n_in,
                              void* d_out, int out_size, void* d_ws, size_t ws_size,
                              hipStream_t stream) {
    const float* x = (const float*)d_in[0];
    const int* ei = (const int*)d_in[1];
    const int* batch = (const int*)d_in[2];
    const float* Wl[3] = {(const float*)d_in[3], (const float*)d_in[6], (const float*)d_in[9]};
    const float* bl[3] = {(const float*)d_in[4], (const float*)d_in[7], (const float*)d_in[10]};
    const float* Wr[3] = {(const float*)d_in[5], (const float*)d_in[8], (const float*)d_in[11]};
    const float* l0W = (const float*)d_in[12];
    const float* l0b = (const float*)d_in[13];
    const float* outW = (const float*)d_in[14];
    const float* outb = (const float*)d_in[15];

    int N = in_sizes[2];
    int E = in_sizes[1] / 2;
    int OUT = 10;
    int G = out_size / OUT;
    const int* src = ei;
    const int* dst = ei + E;
    int NBKT = (N + BNODES - 1) >> BSH;

    char* ws = (char*)d_ws;
    size_t off = 0;
    auto alloc = [&](size_t b) -> char* {
        char* p = ws + off;
        off = (off + b + 255) & ~(size_t)255;
        return p;
    };
    int* row_ptr = (int*)alloc((size_t)(N + 1) * 4);
    int* csr_src = (int*)alloc((size_t)E * 4);
    float* inv_deg = (float*)alloc((size_t)N * 4);
    // contiguous zero region: bkt_cnt | gcnt | gsum (one memset)
    size_t zoff = off;
    int* bkt_cnt = (int*)alloc((size_t)NBKT * 4);
    float* gcnt = (float*)alloc((size_t)G * 4);
    float* gsum = (float*)alloc((size_t)G * 64 * 4);
    size_t zlen = off - zoff;
    int* bkt_base = (int*)alloc((size_t)(NBKT + 1) * 4);
    int* bkt_cur = (int*)alloc((size_t)NBKT * 4);
    unsigned int* pairs = (unsigned int*)alloc((size_t)E * 4);
    __half* hA = (__half*)alloc((size_t)(N + 1) * 64 * 2);  // +1 sentinel row
    __half* hB = (__half*)alloc((size_t)(N + 1) * 64 * 2);

    hipMemsetAsync(ws + zoff, 0, zlen, stream);

    gnn_pre<<<PRE_BLOCKS, 256, 0, stream>>>(dst, bkt_cnt, NBKT, E, batch, gcnt, N, hA, hB);
    gnn_bkt_scan<<<1, 64, 0, stream>>>(bkt_cnt, bkt_base, bkt_cur, row_ptr, NBKT, N);
    gnn_bkt_scatter<<<SC_BLOCKS, 256, 0, stream>>>(src, dst, bkt_cur, pairs, E, NBKT);
    gnn_bkt_csr<<<NBKT, 256, 0, stream>>>(pairs, bkt_base, row_ptr, inv_deg, csr_src, N);

    int ngroups = (N + 15) >> 4;
    int sage_blocks = (ngroups + WPB - 1) / WPB;
    gnn_sage_x<<<sage_blocks, 512, 0, stream>>>(x, hA, row_ptr, csr_src, inv_deg,
                                                Wl[0], bl[0], Wr[0], N);
    gnn_sage<<<sage_blocks, 512, 0, stream>>>(hA, hB, row_ptr, csr_src, inv_deg,
                                              Wl[1], bl[1], Wr[1], N);
    gnn_sage_pool<<<sage_blocks, 512, 0, stream>>>(hB, row_ptr, csr_src, inv_deg,
                                                   Wl[2], bl[2], Wr[2], batch, gsum, N);

    gnn_head<<<1, 256, 0, stream>>>(gsum, gcnt, l0W, l0b, outW, outb, (float*)d_out, G, OUT);
}